// Round 12
// baseline (1194.706 us; speedup 1.0000x reference)
//
#include <hip/hip_runtime.h>
#include <stdint.h>

// ============================================================================
// LSTMDecoder fused — MI355X/gfx950 — R12: 64 rows/WG (halve L2 B-traffic)
//
// R11 analysis: L2-BW-bound (12.9 GB weight stream / 436us = 86% of 34.5TB/s).
// Fix: 64 rows/WG (1024 WGs) halves weight reads. Fit 128 VGPR (2 waves/SIMD)
// via single-gate GEMM passes (acc[4]), bf16-packed c-state/h1 (32 regs each),
// stage1 o-gate deferred. LDS 80KiB: x[64][256] + h[64][256] + t[32][256];
// mix/mid/out phases row-halved through s_t. 2 WGs/CU = 8 waves, indep clocks.
// ============================================================================

typedef __attribute__((ext_vector_type(8))) short bf16x8;
typedef __attribute__((ext_vector_type(4))) float f32x4;

#define OFF_WIH  0         // 3 x 64 tiles (i:0-15 f:16-31 g:32-47 o:48-63)
#define OFF_WHH  786432    // 2 x 64 tiles (a=1,2)
#define OFF_HS   1310720   // 16 tiles
#define OFF_CS   1376256   // 16 tiles
#define OFF_MID  1441792   // 3 x 16 tiles
#define OFF_OUT0 1638400   // 4 tiles
#define OFF_OUT1 1654784   // 2 tiles
#define OFF_OUT2 1662976   // 2 tiles
#define PK_TOTAL 1671168

__device__ __forceinline__ unsigned short f2bf(float f){
  uint32_t u = __float_as_uint(f);
  u += 0x7FFFu + ((u >> 16) & 1u);
  return (unsigned short)(u >> 16);
}
__device__ __forceinline__ float bf2f(unsigned short h){
  return __uint_as_float(((uint32_t)h) << 16);
}
__device__ __forceinline__ uint32_t pk2(float a, float b){
  return (uint32_t)f2bf(a) | ((uint32_t)f2bf(b) << 16);
}
__device__ __forceinline__ float upk(uint32_t u, int hi){
  return __uint_as_float(hi ? (u & 0xFFFF0000u) : (u << 16));
}
__device__ __forceinline__ float sigm(float x){
  return __builtin_amdgcn_rcpf(1.0f + __expf(-x));
}
__device__ __forceinline__ float tanh_(float x){
  return 2.0f * __builtin_amdgcn_rcpf(1.0f + __expf(-2.0f * x)) - 1.0f;
}

// ---------------------------------------------------------------------------
__global__ __launch_bounds__(256)
void pack_all(const float* __restrict__ Wih, const float* __restrict__ Whh,
              const float* __restrict__ hsW, const float* __restrict__ csW,
              const float* __restrict__ midW,
              const float* __restrict__ oW0, const float* __restrict__ oW1,
              const float* __restrict__ oW2,
              unsigned short* __restrict__ pk)
{
  int g = blockIdx.x * 256 + threadIdx.x;
  if (g >= PK_TOTAL / 8) return;
  int tile = g >> 9;
  int within = g & 511;
  int lane = within & 63;
  int kc = within >> 6;

  const float* s; int nt_local, Nsrc;
  if      (tile < 192){ int a = tile / 64; nt_local = tile % 64; s = Wih + (size_t)a * 262144; Nsrc = 1024; }
  else if (tile < 320){ int a = 1 + (tile - 192) / 64; nt_local = (tile - 192) % 64; s = Whh + (size_t)a * 262144; Nsrc = 1024; }
  else if (tile < 336){ nt_local = tile - 320; s = hsW; Nsrc = 256; }
  else if (tile < 352){ nt_local = tile - 336; s = csW; Nsrc = 256; }
  else if (tile < 400){ int a = (tile - 352) / 16; nt_local = (tile - 352) % 16; s = midW + a * 65536; Nsrc = 256; }
  else if (tile < 404){ nt_local = tile - 400; s = oW0; Nsrc = 54; }
  else if (tile < 406){ nt_local = tile - 404; s = oW1; Nsrc = 23; }
  else                { nt_local = tile - 406; s = oW2; Nsrc = 20; }

  int n = nt_local * 16 + (lane & 15);
  int k = kc * 32 + ((lane >> 4) << 3);
  bf16x8 bv;
  if (n < Nsrc){
    const float* sp = s + (size_t)n * 256 + k;
    #pragma unroll
    for (int i = 0; i < 8; ++i) bv[i] = (short)f2bf(sp[i]);
  } else {
    #pragma unroll
    for (int i = 0; i < 8; ++i) bv[i] = 0;
  }
  *(bf16x8*)(pk + (size_t)g * 8) = bv;
}

// ---------------------------------------------------------------------------
// GEMM passes. A tiles XOR-swizzled ((row&7)<<3 in ushort units); row&7==lane&7.
// Lane holds D[(l>>4)*4+r][l&15] per 16x16 tile.

// single-B-tile pass over 64 LDS rows -> acc[4]
__device__ __forceinline__ void gpass(const unsigned short* sA, const unsigned short* pkB,
                                      int tile, int lane, f32x4 (&acc)[4])
{
  const bf16x8* B = (const bf16x8*)pkB;
  const int g16 = (lane >> 4) << 3;
  const int swz = (lane & 7) << 3;
  const int rb  = lane & 15;
  #pragma unroll
  for (int kc = 0; kc < 8; ++kc){
    bf16x8 b = B[tile * 512 + kc * 64 + lane];
    int kcol = (kc * 32 + g16) ^ swz;
    #pragma unroll
    for (int mt = 0; mt < 4; ++mt){
      bf16x8 a = *(const bf16x8*)(sA + (mt * 16 + rb) * 256 + kcol);
      acc[mt] = __builtin_amdgcn_mfma_f32_16x16x32_bf16(a, b, acc[mt], 0, 0, 0);
    }
  }
}

// single-B-tile pass over a 32-row LDS tile (local rows 0..31) -> acc[2]
__device__ __forceinline__ void ghalf2(const unsigned short* sA, const unsigned short* pkB,
                                       int tile, int lane, f32x4 (&acc)[2])
{
  const bf16x8* B = (const bf16x8*)pkB;
  const int g16 = (lane >> 4) << 3;
  const int swz = (lane & 7) << 3;
  const int rb  = lane & 15;
  #pragma unroll
  for (int kc = 0; kc < 8; ++kc){
    bf16x8 b = B[tile * 512 + kc * 64 + lane];
    int kcol = (kc * 32 + g16) ^ swz;
    #pragma unroll
    for (int mtl = 0; mtl < 2; ++mtl){
      bf16x8 a = *(const bf16x8*)(sA + (mtl * 16 + rb) * 256 + kcol);
      acc[mtl] = __builtin_amdgcn_mfma_f32_16x16x32_bf16(a, b, acc[mtl], 0, 0, 0);
    }
  }
}

// single 16-local-row block (mtl) of a 32-row LDS tile
__device__ __forceinline__ void ghalf1(const unsigned short* sA, const unsigned short* pkB,
                                       int tile, int mtl, int lane, f32x4 &acc)
{
  const bf16x8* B = (const bf16x8*)pkB;
  const int g16 = (lane >> 4) << 3;
  const int swz = (lane & 7) << 3;
  const int rb  = mtl * 16 + (lane & 15);
  #pragma unroll
  for (int kc = 0; kc < 8; ++kc){
    bf16x8 b = B[tile * 512 + kc * 64 + lane];
    int kcol = (kc * 32 + g16) ^ swz;
    bf16x8 a = *(const bf16x8*)(sA + rb * 256 + kcol);
    acc = __builtin_amdgcn_mfma_f32_16x16x32_bf16(a, b, acc, 0, 0, 0);
  }
}

// ---------------------------------------------------------------------------
__global__ __launch_bounds__(256, 2)
void lstm_fused(const float* __restrict__ x, const unsigned short* __restrict__ pk,
                const float* __restrict__ bih, const float* __restrict__ bhh,
                const float* __restrict__ hsb, const float* __restrict__ csb,
                const float* __restrict__ midb,
                const float* __restrict__ ob0, const float* __restrict__ ob1,
                const float* __restrict__ ob2, float* __restrict__ out)
{
  __shared__ __align__(16) unsigned short smem[40960];   // 80 KiB -> 2 WG/CU
  unsigned short* s_x = smem;            // [64][256] x bf16
  unsigned short* s_h = smem + 16384;    // [64][256] h0 -> hh -> h2
  unsigned short* s_t = smem + 32768;    // [32][256] temp (halves) + f32 out

  const int tid  = threadIdx.x;
  const int lane = tid & 63;
  const int w    = tid >> 6;              // col quarter 0..3
  const int row0 = blockIdx.x * 64;
  const int rsub = (lane >> 4) << 2;
  const int jl   = lane & 15;

  // ---- stage x (64 rows) f32 -> bf16 swizzled
  {
    const float* xg = x + (size_t)row0 * 256;
    #pragma unroll
    for (int it = 0; it < 8; ++it){
      int idx = it * 2048 + tid * 8;
      int row = idx >> 8, col = idx & 255;
      float4 v0 = *(const float4*)(xg + idx);
      float4 v1 = *(const float4*)(xg + idx + 4);
      bf16x8 bv;
      bv[0]=(short)f2bf(v0.x); bv[1]=(short)f2bf(v0.y); bv[2]=(short)f2bf(v0.z); bv[3]=(short)f2bf(v0.w);
      bv[4]=(short)f2bf(v1.x); bv[5]=(short)f2bf(v1.y); bv[6]=(short)f2bf(v1.z); bv[7]=(short)f2bf(v1.w);
      *(bf16x8*)(s_x + row * 256 + (col ^ ((row & 7) << 3))) = bv;
    }
  }
  __syncthreads();

  uint32_t c0p[4][4][2];   // c-state bf16-packed: [t][mt][rpair]
  uint32_t h1p[4][4][2];   // h1 (later h2) bf16-packed

  // ======== STAGE 0: gates i,g,o from x (f dead)
  #pragma unroll
  for (int t = 0; t < 4; ++t){
    int nt = w * 4 + t, j = w * 64 + t * 16 + jl;
    float bi = bih[j] + bhh[j];
    float bg = bih[512 + j] + bhh[512 + j];
    float bo = bih[768 + j] + bhh[768 + j];
    f32x4 ai[4] = {}, ag[4] = {}, ao4[4] = {};
    gpass(s_x, pk + OFF_WIH, nt,      lane, ai);
    gpass(s_x, pk + OFF_WIH, 32 + nt, lane, ag);
    gpass(s_x, pk + OFF_WIH, 48 + nt, lane, ao4);
    #pragma unroll
    for (int mt = 0; mt < 4; ++mt){
      float cv[4];
      #pragma unroll
      for (int r = 0; r < 4; ++r){
        float c = sigm(ai[mt][r] + bi) * tanh_(ag[mt][r] + bg);
        float h = sigm(ao4[mt][r] + bo) * tanh_(c);
        cv[r] = c;
        int m = mt * 16 + rsub + r;
        s_h[m * 256 + (j ^ ((m & 7) << 3))] = f2bf(h);
      }
      c0p[t][mt][0] = pk2(cv[0], cv[1]);
      c0p[t][mt][1] = pk2(cv[2], cv[3]);
    }
  }
  __syncthreads();

  // ======== MID0 (full rows from s_h) + OUT0 (halves via s_t)
  {
    f32x4 mhi[4][2];
    #pragma unroll
    for (int t = 0; t < 4; ++t){
      int nt = w * 4 + t, j = w * 64 + t * 16 + jl;
      f32x4 am[4] = {};
      gpass(s_h, pk + OFF_MID, nt, lane, am);
      float mb = midb[j];
      #pragma unroll
      for (int mt = 0; mt < 2; ++mt)
        #pragma unroll
        for (int r = 0; r < 4; ++r){
          float v = am[mt][r] + mb; v = v > 0.f ? v : 0.f;
          int m = mt * 16 + rsub + r;
          s_t[m * 256 + (j ^ ((m & 7) << 3))] = f2bf(v);
        }
      #pragma unroll
      for (int mtl = 0; mtl < 2; ++mtl)
        #pragma unroll
        for (int r = 0; r < 4; ++r){
          float v = am[2 + mtl][r] + mb; mhi[t][mtl][r] = v > 0.f ? v : 0.f;
        }
    }
    __syncthreads();
    #pragma unroll
    for (int hf = 0; hf < 2; ++hf){
      f32x4 ao2[2] = {};
      ghalf2(s_t, pk + OFF_OUT0, w, lane, ao2);
      __syncthreads();
      float* s_of = (float*)s_t;
      int colc = w * 16 + jl;
      if (colc < 54){
        float ob = ob0[colc];
        #pragma unroll
        for (int mtl = 0; mtl < 2; ++mtl)
          #pragma unroll
          for (int r = 0; r < 4; ++r){
            int m = mtl * 16 + rsub + r;
            s_of[m * 54 + colc] = ao2[mtl][r] + ob;
          }
      }
      __syncthreads();
      float4* op = (float4*)(out + ((size_t)row0 + hf * 32) * 54);
      const float4* s4 = (const float4*)s_of;
      for (int e = tid; e < 432; e += 256) op[e] = s4[e];
      __syncthreads();
      if (hf == 0){
        #pragma unroll
        for (int t = 0; t < 4; ++t){
          int j = w * 64 + t * 16 + jl;
          #pragma unroll
          for (int mtl = 0; mtl < 2; ++mtl)
            #pragma unroll
            for (int r = 0; r < 4; ++r){
              int m = mtl * 16 + rsub + r;
              s_t[m * 256 + (j ^ ((m & 7) << 3))] = f2bf(mhi[t][mtl][r]);
            }
        }
        __syncthreads();
      }
    }
  }

  uint32_t c1p[4][4][2];

  // ======== STAGE 1: gates i,f,g (o deferred) -> c1
  #pragma unroll
  for (int t = 0; t < 4; ++t){
    int nt = w * 4 + t, j = w * 64 + t * 16 + jl;
    float bi = bih[1024 + j] + bhh[1024 + j];
    float bf_= bih[1280 + j] + bhh[1280 + j];
    float bg = bih[1536 + j] + bhh[1536 + j];
    uint32_t sip[4][2], sfp[4][2];
    {
      f32x4 a4[4] = {};
      gpass(s_x, pk + OFF_WIH + 262144, nt, lane, a4);
      gpass(s_h, pk + OFF_WHH,          nt, lane, a4);
      #pragma unroll
      for (int mt = 0; mt < 4; ++mt){
        sip[mt][0] = pk2(sigm(a4[mt][0] + bi), sigm(a4[mt][1] + bi));
        sip[mt][1] = pk2(sigm(a4[mt][2] + bi), sigm(a4[mt][3] + bi));
      }
    }
    {
      f32x4 a4[4] = {};
      gpass(s_x, pk + OFF_WIH + 262144, 16 + nt, lane, a4);
      gpass(s_h, pk + OFF_WHH,          16 + nt, lane, a4);
      #pragma unroll
      for (int mt = 0; mt < 4; ++mt){
        sfp[mt][0] = pk2(sigm(a4[mt][0] + bf_), sigm(a4[mt][1] + bf_));
        sfp[mt][1] = pk2(sigm(a4[mt][2] + bf_), sigm(a4[mt][3] + bf_));
      }
    }
    {
      f32x4 a4[4] = {};
      gpass(s_x, pk + OFF_WIH + 262144, 32 + nt, lane, a4);
      gpass(s_h, pk + OFF_WHH,          32 + nt, lane, a4);
      #pragma unroll
      for (int mt = 0; mt < 4; ++mt){
        float cv[4];
        #pragma unroll
        for (int r = 0; r < 4; ++r){
          float g = tanh_(a4[mt][r] + bg);
          cv[r] = upk(sfp[mt][r >> 1], r & 1) * upk(c0p[t][mt][r >> 1], r & 1)
                + upk(sip[mt][r >> 1], r & 1) * g;
        }
        c1p[t][mt][0] = pk2(cv[0], cv[1]);
        c1p[t][mt][1] = pk2(cv[2], cv[3]);
      }
    }
  }

  // ======== CS mix (halves): cc = c0 + c1*csW^T + csb  (acc-init = c0+csb)
  #pragma unroll
  for (int hf = 0; hf < 2; ++hf){
    #pragma unroll
    for (int t = 0; t < 4; ++t){
      int j = w * 64 + t * 16 + jl;
      #pragma unroll
      for (int mtl = 0; mtl < 2; ++mtl)
        #pragma unroll
        for (int pr = 0; pr < 2; ++pr){
          uint32_t u = c1p[t][hf * 2 + mtl][pr];
          int m0 = mtl * 16 + rsub + 2 * pr;
          s_t[m0 * 256 + (j ^ ((m0 & 7) << 3))] = (unsigned short)(u & 0xFFFF);
          int m1 = m0 + 1;
          s_t[m1 * 256 + (j ^ ((m1 & 7) << 3))] = (unsigned short)(u >> 16);
        }
    }
    __syncthreads();
    #pragma unroll
    for (int t = 0; t < 4; ++t){
      int nt = w * 4 + t, j = w * 64 + t * 16 + jl;
      float cb = csb[j];
      f32x4 ac2[2];
      #pragma unroll
      for (int mtl = 0; mtl < 2; ++mtl)
        #pragma unroll
        for (int r = 0; r < 4; ++r)
          ac2[mtl][r] = upk(c0p[t][hf * 2 + mtl][r >> 1], r & 1) + cb;
      ghalf2(s_t, pk + OFF_CS, nt, lane, ac2);
      #pragma unroll
      for (int mtl = 0; mtl < 2; ++mtl){
        c0p[t][hf * 2 + mtl][0] = pk2(ac2[mtl][0], ac2[mtl][1]);
        c0p[t][hf * 2 + mtl][1] = pk2(ac2[mtl][2], ac2[mtl][3]);
      }
    }
    __syncthreads();
  }

  // ======== deferred o-gate of stage 1 -> h1
  #pragma unroll
  for (int t = 0; t < 4; ++t){
    int nt = w * 4 + t, j = w * 64 + t * 16 + jl;
    float bo = bih[1792 + j] + bhh[1792 + j];
    f32x4 a4[4] = {};
    gpass(s_x, pk + OFF_WIH + 262144, 48 + nt, lane, a4);
    gpass(s_h, pk + OFF_WHH,          48 + nt, lane, a4);
    #pragma unroll
    for (int mt = 0; mt < 4; ++mt){
      float hv[4];
      #pragma unroll
      for (int r = 0; r < 4; ++r)
        hv[r] = sigm(a4[mt][r] + bo) * tanh_(upk(c1p[t][mt][r >> 1], r & 1));
      h1p[t][mt][0] = pk2(hv[0], hv[1]);
      h1p[t][mt][1] = pk2(hv[2], hv[3]);
    }
  }

  // ======== per half: h1 -> s_t; HS mix (update s_h) + MID1; OUT1
  #pragma unroll
  for (int hf = 0; hf < 2; ++hf){
    #pragma unroll
    for (int t = 0; t < 4; ++t){
      int j = w * 64 + t * 16 + jl;
      #pragma unroll
      for (int mtl = 0; mtl < 2; ++mtl)
        #pragma unroll
        for (int pr = 0; pr < 2; ++pr){
          uint32_t u = h1p[t][hf * 2 + mtl][pr];
          int m0 = mtl * 16 + rsub + 2 * pr;
          s_t[m0 * 256 + (j ^ ((m0 & 7) << 3))] = (unsigned short)(u & 0xFFFF);
          int m1 = m0 + 1;
          s_t[m1 * 256 + (j ^ ((m1 & 7) << 3))] = (unsigned short)(u >> 16);
        }
    }
    __syncthreads();
    f32x4 m1h[4][2];
    #pragma unroll
    for (int t = 0; t < 4; ++t){
      int nt = w * 4 + t, j = w * 64 + t * 16 + jl;
      // HS: hh = h0 + h1*hsW^T + hsb (in-place s_h, own slots)
      f32x4 ah2[2] = {};
      ghalf2(s_t, pk + OFF_HS, nt, lane, ah2);
      float hb = hsb[j];
      #pragma unroll
      for (int mtl = 0; mtl < 2; ++mtl)
        #pragma unroll
        for (int r = 0; r < 4; ++r){
          int mg = hf * 32 + mtl * 16 + rsub + r;
          int ofs = mg * 256 + (j ^ ((mg & 7) << 3));
          s_h[ofs] = f2bf(bf2f(s_h[ofs]) + ah2[mtl][r] + hb);
        }
      // MID1 from h1 (s_t)
      f32x4 am2[2] = {};
      ghalf2(s_t, pk + OFF_MID + 65536, nt, lane, am2);
      float mb = midb[256 + j];
      #pragma unroll
      for (int mtl = 0; mtl < 2; ++mtl)
        #pragma unroll
        for (int r = 0; r < 4; ++r){
          float v = am2[mtl][r] + mb; m1h[t][mtl][r] = v > 0.f ? v : 0.f;
        }
    }
    __syncthreads();
    #pragma unroll
    for (int t = 0; t < 4; ++t){
      int j = w * 64 + t * 16 + jl;
      #pragma unroll
      for (int mtl = 0; mtl < 2; ++mtl)
        #pragma unroll
        for (int r = 0; r < 4; ++r){
          int m = mtl * 16 + rsub + r;
          s_t[m * 256 + (j ^ ((m & 7) << 3))] = f2bf(m1h[t][mtl][r]);
        }
    }
    __syncthreads();
    {
      f32x4 ao = {0.f, 0.f, 0.f, 0.f};
      ghalf1(s_t, pk + OFF_OUT1, w & 1, w >> 1, lane, ao);
      __syncthreads();
      float* s_of = (float*)s_t;
      int colc = (w & 1) * 16 + jl;
      if (colc < 23){
        float ob = ob1[colc];
        #pragma unroll
        for (int r = 0; r < 4; ++r){
          int m = (w >> 1) * 16 + rsub + r;
          s_of[m * 23 + colc] = ao[r] + ob;
        }
      }
      __syncthreads();
      float4* op = (float4*)(out + 3538944 + ((size_t)row0 + hf * 32) * 23);
      const float4* s4 = (const float4*)s_of;
      for (int e = tid; e < 184; e += 256) op[e] = s4[e];
      __syncthreads();
    }
  }

  // ======== STAGE 2: gates i,f,g (cc in c0p, overwritten by c2) + inline o -> h2
  #pragma unroll
  for (int t = 0; t < 4; ++t){
    int nt = w * 4 + t, j = w * 64 + t * 16 + jl;
    float bi = bih[2048 + j] + bhh[2048 + j];
    float bf_= bih[2304 + j] + bhh[2304 + j];
    float bg = bih[2560 + j] + bhh[2560 + j];
    float bo = bih[2816 + j] + bhh[2816 + j];
    uint32_t sip[4][2], sfp[4][2];
    {
      f32x4 a4[4] = {};
      gpass(s_x, pk + OFF_WIH + 524288, nt, lane, a4);
      gpass(s_h, pk + OFF_WHH + 262144, nt, lane, a4);
      #pragma unroll
      for (int mt = 0; mt < 4; ++mt){
        sip[mt][0] = pk2(sigm(a4[mt][0] + bi), sigm(a4[mt][1] + bi));
        sip[mt][1] = pk2(sigm(a4[mt][2] + bi), sigm(a4[mt][3] + bi));
      }
    }
    {
      f32x4 a4[4] = {};
      gpass(s_x, pk + OFF_WIH + 524288, 16 + nt, lane, a4);
      gpass(s_h, pk + OFF_WHH + 262144, 16 + nt, lane, a4);
      #pragma unroll
      for (int mt = 0; mt < 4; ++mt){
        sfp[mt][0] = pk2(sigm(a4[mt][0] + bf_), sigm(a4[mt][1] + bf_));
        sfp[mt][1] = pk2(sigm(a4[mt][2] + bf_), sigm(a4[mt][3] + bf_));
      }
    }
    {
      f32x4 a4[4] = {};
      gpass(s_x, pk + OFF_WIH + 524288, 32 + nt, lane, a4);
      gpass(s_h, pk + OFF_WHH + 262144, 32 + nt, lane, a4);
      #pragma unroll
      for (int mt = 0; mt < 4; ++mt){
        float cv[4];
        #pragma unroll
        for (int r = 0; r < 4; ++r){
          float g = tanh_(a4[mt][r] + bg);
          cv[r] = upk(sfp[mt][r >> 1], r & 1) * upk(c0p[t][mt][r >> 1], r & 1)
                + upk(sip[mt][r >> 1], r & 1) * g;
        }
        c0p[t][mt][0] = pk2(cv[0], cv[1]);   // c2
        c0p[t][mt][1] = pk2(cv[2], cv[3]);
      }
    }
    {
      f32x4 a4[4] = {};
      gpass(s_x, pk + OFF_WIH + 524288, 48 + nt, lane, a4);
      gpass(s_h, pk + OFF_WHH + 262144, 48 + nt, lane, a4);
      #pragma unroll
      for (int mt = 0; mt < 4; ++mt){
        float hv[4];
        #pragma unroll
        for (int r = 0; r < 4; ++r)
          hv[r] = sigm(a4[mt][r] + bo) * tanh_(upk(c0p[t][mt][r >> 1], r & 1));
        h1p[t][mt][0] = pk2(hv[0], hv[1]);   // h2
        h1p[t][mt][1] = pk2(hv[2], hv[3]);
      }
    }
  }
  __syncthreads();

  // h2 -> s_h (hh dead)
  #pragma unroll
  for (int t = 0; t < 4; ++t){
    int j = w * 64 + t * 16 + jl;
    #pragma unroll
    for (int mt = 0; mt < 4; ++mt)
      #pragma unroll
      for (int pr = 0; pr < 2; ++pr){
        uint32_t u = h1p[t][mt][pr];
        int m0 = mt * 16 + rsub + 2 * pr;
        s_h[m0 * 256 + (j ^ ((m0 & 7) << 3))] = (unsigned short)(u & 0xFFFF);
        int m1 = m0 + 1;
        s_h[m1 * 256 + (j ^ ((m1 & 7) << 3))] = (unsigned short)(u >> 16);
      }
  }
  __syncthreads();

  // ======== MID2 (full rows from s_h) + OUT2 (halves via s_t)
  {
    f32x4 mhi[4][2];
    #pragma unroll
    for (int t = 0; t < 4; ++t){
      int nt = w * 4 + t, j = w * 64 + t * 16 + jl;
      f32x4 am[4] = {};
      gpass(s_h, pk + OFF_MID + 131072, nt, lane, am);
      float mb = midb[512 + j];
      #pragma unroll
      for (int mt = 0; mt < 2; ++mt)
        #pragma unroll
        for (int r = 0; r < 4; ++r){
          float v = am[mt][r] + mb; v = v > 0.f ? v : 0.f;
          int m = mt * 16 + rsub + r;
          s_t[m * 256 + (j ^ ((m & 7) << 3))] = f2bf(v);
        }
      #pragma unroll
      for (int mtl = 0; mtl < 2; ++mtl)
        #pragma unroll
        for (int r = 0; r < 4; ++r){
          float v = am[2 + mtl][r] + mb; mhi[t][mtl][r] = v > 0.f ? v : 0.f;
        }
    }
    __syncthreads();
    #pragma unroll
    for (int hf = 0; hf < 2; ++hf){
      f32x4 ao = {0.f, 0.f, 0.f, 0.f};
      ghalf1(s_t, pk + OFF_OUT2, w & 1, w >> 1, lane, ao);
      __syncthreads();
      float* s_of = (float*)s_t;
      int colc = (w & 1) * 16 + jl;
      if (colc < 20){
        float ob = ob2[colc];
        #pragma unroll
        for (int r = 0; r < 4; ++r){
          int m = (w >> 1) * 16 + rsub + r;
          s_of[m * 20 + colc] = ao[r] + ob;
        }
      }
      __syncthreads();
      float4* op = (float4*)(out + 5046272 + ((size_t)row0 + hf * 32) * 20);
      const float4* s4 = (const float4*)s_of;
      for (int e = tid; e < 160; e += 256) op[e] = s4[e];
      __syncthreads();
      if (hf == 0){
        #pragma unroll
        for (int t = 0; t < 4; ++t){
          int j = w * 64 + t * 16 + jl;
          #pragma unroll
          for (int mtl = 0; mtl < 2; ++mtl)
            #pragma unroll
            for (int r = 0; r < 4; ++r){
              int m = mtl * 16 + rsub + r;
              s_t[m * 256 + (j ^ ((m & 7) << 3))] = f2bf(mhi[t][mtl][r]);
            }
        }
        __syncthreads();
      }
    }
  }
}

extern "C" void kernel_launch(void* const* d_in, const int* in_sizes, int n_in,
                              void* d_out, int out_size, void* d_ws, size_t ws_size,
                              hipStream_t stream)
{
  const float* x     = (const float*)d_in[0];
  const float* Wih   = (const float*)d_in[1];
  const float* Whh   = (const float*)d_in[2];
  const float* bih   = (const float*)d_in[3];
  const float* bhh   = (const float*)d_in[4];
  const float* hsW   = (const float*)d_in[5];
  const float* hsb   = (const float*)d_in[6];
  const float* csW   = (const float*)d_in[7];
  const float* csb   = (const float*)d_in[8];
  const float* midW  = (const float*)d_in[9];
  const float* midb  = (const float*)d_in[10];
  const float* outW0 = (const float*)d_in[11];
  const float* outb0 = (const float*)d_in[12];
  const float* outW1 = (const float*)d_in[13];
  const float* outb1 = (const float*)d_in[14];
  const float* outW2 = (const float*)d_in[15];
  const float* outb2 = (const float*)d_in[16];

  unsigned short* pk = (unsigned short*)d_ws;

  int ngroups = PK_TOTAL / 8;
  pack_all<<<(ngroups + 255) / 256, 256, 0, stream>>>(
      Wih, Whh, hsW + 5 * 65536, csW + 5 * 65536, midW, outW0, outW1, outW2, pk);

  lstm_fused<<<1024, 256, 0, stream>>>(
      x, pk, bih, bhh, hsb + 5 * 256, csb + 5 * 256, midb,
      outb0, outb1, outb2, (float*)d_out);
}

// Round 13
// 736.208 us; speedup vs baseline: 1.6228x; 1.6228x over previous
//
#include <hip/hip_runtime.h>
#include <stdint.h>

// ============================================================================
// LSTMDecoder fused — MI355X/gfx950 — R13: 12 waves/CU (3 WGs x (256,3))
//
// R11 = 398us, latency-bound: MFMA 21.5%, VALU 39%, L2 45% — nothing
// saturated at 8 waves/CU. Occupancy law (validated R2-R11):
// waves/SIMD = floor(256/VGPR); cap = 256/max(arg2, blk/256).
// -> VGPR<=84 via (256,3) + LDS 48KB -> 3 WGs/CU = 12 waves.
// R12's spill lesson: keep ONE persistent packed state (c0p, 16 regs);
// single-gate passes (acc[2]=8); c1/h1/h2/m1/m2 cycle through one LDS temp.
// Peak live ~60 regs.
// ============================================================================

typedef __attribute__((ext_vector_type(8))) short bf16x8;
typedef __attribute__((ext_vector_type(4))) float f32x4;

#define OFF_WIH  0         // 3 x 64 tiles (i:0-15 f:16-31 g:32-47 o:48-63)
#define OFF_WHH  786432    // 2 x 64 tiles (a=1,2)
#define OFF_HS   1310720   // 16 tiles
#define OFF_CS   1376256   // 16 tiles
#define OFF_MID  1441792   // 3 x 16 tiles
#define OFF_OUT0 1638400   // 4 tiles
#define OFF_OUT1 1654784   // 2 tiles
#define OFF_OUT2 1662976   // 2 tiles
#define PK_TOTAL 1671168

__device__ __forceinline__ unsigned short f2bf(float f){
  uint32_t u = __float_as_uint(f);
  u += 0x7FFFu + ((u >> 16) & 1u);
  return (unsigned short)(u >> 16);
}
__device__ __forceinline__ float bf2f(unsigned short h){
  return __uint_as_float(((uint32_t)h) << 16);
}
__device__ __forceinline__ uint32_t pk2(float a, float b){
  return (uint32_t)f2bf(a) | ((uint32_t)f2bf(b) << 16);
}
__device__ __forceinline__ float upk(uint32_t u, int hi){
  return __uint_as_float(hi ? (u & 0xFFFF0000u) : (u << 16));
}
__device__ __forceinline__ float sigm(float x){
  return __builtin_amdgcn_rcpf(1.0f + __expf(-x));
}
__device__ __forceinline__ float tanh_(float x){
  return 2.0f * __builtin_amdgcn_rcpf(1.0f + __expf(-2.0f * x)) - 1.0f;
}

// ---------------------------------------------------------------------------
__global__ __launch_bounds__(256)
void pack_all(const float* __restrict__ Wih, const float* __restrict__ Whh,
              const float* __restrict__ hsW, const float* __restrict__ csW,
              const float* __restrict__ midW,
              const float* __restrict__ oW0, const float* __restrict__ oW1,
              const float* __restrict__ oW2,
              unsigned short* __restrict__ pk)
{
  int g = blockIdx.x * 256 + threadIdx.x;
  if (g >= PK_TOTAL / 8) return;
  int tile = g >> 9;
  int within = g & 511;
  int lane = within & 63;
  int kc = within >> 6;

  const float* s; int nt_local, Nsrc;
  if      (tile < 192){ int a = tile / 64; nt_local = tile % 64; s = Wih + (size_t)a * 262144; Nsrc = 1024; }
  else if (tile < 320){ int a = 1 + (tile - 192) / 64; nt_local = (tile - 192) % 64; s = Whh + (size_t)a * 262144; Nsrc = 1024; }
  else if (tile < 336){ nt_local = tile - 320; s = hsW; Nsrc = 256; }
  else if (tile < 352){ nt_local = tile - 336; s = csW; Nsrc = 256; }
  else if (tile < 400){ int a = (tile - 352) / 16; nt_local = (tile - 352) % 16; s = midW + a * 65536; Nsrc = 256; }
  else if (tile < 404){ nt_local = tile - 400; s = oW0; Nsrc = 54; }
  else if (tile < 406){ nt_local = tile - 404; s = oW1; Nsrc = 23; }
  else                { nt_local = tile - 406; s = oW2; Nsrc = 20; }

  int n = nt_local * 16 + (lane & 15);
  int k = kc * 32 + ((lane >> 4) << 3);
  bf16x8 bv;
  if (n < Nsrc){
    const float* sp = s + (size_t)n * 256 + k;
    #pragma unroll
    for (int i = 0; i < 8; ++i) bv[i] = (short)f2bf(sp[i]);
  } else {
    #pragma unroll
    for (int i = 0; i < 8; ++i) bv[i] = 0;
  }
  *(bf16x8*)(pk + (size_t)g * 8) = bv;
}

// ---------------------------------------------------------------------------
// A: LDS [32 rows][256 k] bf16, XOR-swizzled ((row&7)<<3 in ushort units).
// B: packed frag tiles. Lane holds D[(l>>4)*4+r][l&15] per 16x16 tile.

// one B-tile over 32 rows -> acc[2] (accumulating)
__device__ __forceinline__ void gemm1(const unsigned short* sA, const unsigned short* pkB,
                                      int nt, int lane, f32x4 (&acc)[2])
{
  const bf16x8* B = (const bf16x8*)pkB;
  const int g16 = (lane >> 4) << 3;
  const int swz = (lane & 7) << 3;
  const int rb  = lane & 15;
  #pragma unroll
  for (int kc = 0; kc < 8; ++kc){
    bf16x8 b = B[nt * 512 + kc * 64 + lane];
    int kcol = (kc * 32 + g16) ^ swz;
    #pragma unroll
    for (int mt = 0; mt < 2; ++mt){
      bf16x8 a = *(const bf16x8*)(sA + (mt * 16 + rb) * 256 + kcol);
      acc[mt] = __builtin_amdgcn_mfma_f32_16x16x32_bf16(a, b, acc[mt], 0, 0, 0);
    }
  }
}

// one B-tile, single 16-row block mh (0/1)
__device__ __forceinline__ void gemm1q(const unsigned short* sA, const unsigned short* pkB,
                                       int nt, int mh, int lane, f32x4 &acc)
{
  const bf16x8* B = (const bf16x8*)pkB;
  const int g16 = (lane >> 4) << 3;
  const int swz = (lane & 7) << 3;
  const int rb  = mh * 16 + (lane & 15);
  #pragma unroll
  for (int kc = 0; kc < 8; ++kc){
    bf16x8 b = B[nt * 512 + kc * 64 + lane];
    int kcol = (kc * 32 + g16) ^ swz;
    bf16x8 a = *(const bf16x8*)(sA + rb * 256 + kcol);
    acc = __builtin_amdgcn_mfma_f32_16x16x32_bf16(a, b, acc, 0, 0, 0);
  }
}

// ---------------------------------------------------------------------------
// (256,3): VGPR cap 84 -> 3 waves/SIMD; 48 KiB LDS -> 3 WGs/CU = 12 waves.
__global__ __launch_bounds__(256, 3)
void lstm_fused(const float* __restrict__ x, const unsigned short* __restrict__ pk,
                const float* __restrict__ bih, const float* __restrict__ bhh,
                const float* __restrict__ hsb, const float* __restrict__ csb,
                const float* __restrict__ midb,
                const float* __restrict__ ob0, const float* __restrict__ ob1,
                const float* __restrict__ ob2, float* __restrict__ out)
{
  __shared__ __align__(16) unsigned short smem[24576];   // 48 KiB
  unsigned short* s_x = smem;            // [32][256] x
  unsigned short* s_h = smem + 8192;     // [32][256] h0 -> hh (stage2 A-src)
  unsigned short* s_b = smem + 16384;    // [32][256] temp: m0/out/c1/h1/m1/h2/m2

  const int tid  = threadIdx.x;
  const int lane = tid & 63;
  const int w    = tid >> 6;              // col quarter 0..3
  const int row0 = blockIdx.x * 32;
  const int rsub = (lane >> 4) << 2;
  const int jl   = lane & 15;

  // ---- stage x: f32 -> bf16 swizzled
  {
    const float* xg = x + (size_t)row0 * 256;
    #pragma unroll
    for (int it = 0; it < 4; ++it){
      int idx = it * 2048 + tid * 8;
      int row = idx >> 8, col = idx & 255;
      float4 v0 = *(const float4*)(xg + idx);
      float4 v1 = *(const float4*)(xg + idx + 4);
      bf16x8 bv;
      bv[0]=(short)f2bf(v0.x); bv[1]=(short)f2bf(v0.y); bv[2]=(short)f2bf(v0.z); bv[3]=(short)f2bf(v0.w);
      bv[4]=(short)f2bf(v1.x); bv[5]=(short)f2bf(v1.y); bv[6]=(short)f2bf(v1.z); bv[7]=(short)f2bf(v1.w);
      *(bf16x8*)(s_x + row * 256 + (col ^ ((row & 7) << 3))) = bv;
    }
  }
  __syncthreads();

  uint32_t c0p[4][2][2];   // ONLY persistent reg state: c0 -> cc (bf16-packed)

  // ======== STAGE0: i,g,o from x (f dead); c0 -> c0p, h0 -> s_h
  #pragma unroll
  for (int t = 0; t < 4; ++t){
    int nt = w * 4 + t, j = w * 64 + t * 16 + jl;
    f32x4 ai[2] = {}, ag[2] = {}, ao[2] = {};
    gemm1(s_x, pk + OFF_WIH, nt,      lane, ai);
    gemm1(s_x, pk + OFF_WIH, 32 + nt, lane, ag);
    gemm1(s_x, pk + OFF_WIH, 48 + nt, lane, ao);
    float bi = bih[j] + bhh[j];
    float bg = bih[512 + j] + bhh[512 + j];
    float bo = bih[768 + j] + bhh[768 + j];
    #pragma unroll
    for (int mt = 0; mt < 2; ++mt){
      float cv[4];
      #pragma unroll
      for (int r = 0; r < 4; ++r){
        float c = sigm(ai[mt][r] + bi) * tanh_(ag[mt][r] + bg);
        float h = sigm(ao[mt][r] + bo) * tanh_(c);
        cv[r] = c;
        int m = mt * 16 + rsub + r;
        s_h[m * 256 + (j ^ ((m & 7) << 3))] = f2bf(h);
      }
      c0p[t][mt][0] = pk2(cv[0], cv[1]);
      c0p[t][mt][1] = pk2(cv[2], cv[3]);
    }
  }
  __syncthreads();

  // ======== MID0: relu(h0*midW0^T + b) -> s_b
  #pragma unroll
  for (int t = 0; t < 4; ++t){
    int nt = w * 4 + t, j = w * 64 + t * 16 + jl;
    f32x4 am[2] = {};
    gemm1(s_h, pk + OFF_MID, nt, lane, am);
    float mb = midb[j];
    #pragma unroll
    for (int mt = 0; mt < 2; ++mt)
      #pragma unroll
      for (int r = 0; r < 4; ++r){
        float v = am[mt][r] + mb; v = v > 0.f ? v : 0.f;
        int m = mt * 16 + rsub + r;
        s_b[m * 256 + (j ^ ((m & 7) << 3))] = f2bf(v);
      }
  }
  __syncthreads();

  // ======== OUT0 (54 cols)
  {
    f32x4 ao2[2] = {};
    gemm1(s_b, pk + OFF_OUT0, w, lane, ao2);
    __syncthreads();
    float* s_of = (float*)s_b;
    int colc = w * 16 + jl;
    if (colc < 54){
      float ob = ob0[colc];
      #pragma unroll
      for (int mt = 0; mt < 2; ++mt)
        #pragma unroll
        for (int r = 0; r < 4; ++r){
          int m = mt * 16 + rsub + r;
          s_of[m * 54 + colc] = ao2[mt][r] + ob;
        }
    }
    __syncthreads();
    float4* op = (float4*)(out + (size_t)row0 * 54);
    const float4* s4 = (const float4*)s_of;
    for (int e = tid; e < 432; e += 256) op[e] = s4[e];
  }
  __syncthreads();

  // ======== STAGE1: i,f,g (o deferred); c1 -> s_b
  #pragma unroll
  for (int t = 0; t < 4; ++t){
    int nt = w * 4 + t, j = w * 64 + t * 16 + jl;
    uint32_t sip[2][2], sfp[2][2];
    {
      f32x4 a2[2] = {};
      gemm1(s_x, pk + OFF_WIH + 262144, nt, lane, a2);
      gemm1(s_h, pk + OFF_WHH,          nt, lane, a2);
      float bi = bih[1024 + j] + bhh[1024 + j];
      #pragma unroll
      for (int mt = 0; mt < 2; ++mt){
        sip[mt][0] = pk2(sigm(a2[mt][0] + bi), sigm(a2[mt][1] + bi));
        sip[mt][1] = pk2(sigm(a2[mt][2] + bi), sigm(a2[mt][3] + bi));
      }
    }
    {
      f32x4 a2[2] = {};
      gemm1(s_x, pk + OFF_WIH + 262144, 16 + nt, lane, a2);
      gemm1(s_h, pk + OFF_WHH,          16 + nt, lane, a2);
      float bf_ = bih[1280 + j] + bhh[1280 + j];
      #pragma unroll
      for (int mt = 0; mt < 2; ++mt){
        sfp[mt][0] = pk2(sigm(a2[mt][0] + bf_), sigm(a2[mt][1] + bf_));
        sfp[mt][1] = pk2(sigm(a2[mt][2] + bf_), sigm(a2[mt][3] + bf_));
      }
    }
    {
      f32x4 a2[2] = {};
      gemm1(s_x, pk + OFF_WIH + 262144, 32 + nt, lane, a2);
      gemm1(s_h, pk + OFF_WHH,          32 + nt, lane, a2);
      float bg = bih[1536 + j] + bhh[1536 + j];
      #pragma unroll
      for (int mt = 0; mt < 2; ++mt)
        #pragma unroll
        for (int r = 0; r < 4; ++r){
          float c1 = upk(sfp[mt][r >> 1], r & 1) * upk(c0p[t][mt][r >> 1], r & 1)
                   + upk(sip[mt][r >> 1], r & 1) * tanh_(a2[mt][r] + bg);
          int m = mt * 16 + rsub + r;
          s_b[m * 256 + (j ^ ((m & 7) << 3))] = f2bf(c1);
        }
    }
  }
  __syncthreads();

  // ======== CS mix: cc = c0 + c1*csW^T + csb (acc init = c0+csb) -> c0p
  #pragma unroll
  for (int t = 0; t < 4; ++t){
    int nt = w * 4 + t, j = w * 64 + t * 16 + jl;
    float cb = csb[j];
    f32x4 ac[2];
    #pragma unroll
    for (int mt = 0; mt < 2; ++mt)
      #pragma unroll
      for (int r = 0; r < 4; ++r)
        ac[mt][r] = upk(c0p[t][mt][r >> 1], r & 1) + cb;
    gemm1(s_b, pk + OFF_CS, nt, lane, ac);
    #pragma unroll
    for (int mt = 0; mt < 2; ++mt){
      c0p[t][mt][0] = pk2(ac[mt][0], ac[mt][1]);
      c0p[t][mt][1] = pk2(ac[mt][2], ac[mt][3]);
    }
  }
  __syncthreads();

  // ======== deferred stage-1 o-gate: h1 = sigm(o)*tanh(c1); s_b: c1 -> h1
  #pragma unroll
  for (int t = 0; t < 4; ++t){
    int nt = w * 4 + t, j = w * 64 + t * 16 + jl;
    f32x4 a2[2] = {};
    gemm1(s_x, pk + OFF_WIH + 262144, 48 + nt, lane, a2);
    gemm1(s_h, pk + OFF_WHH,          48 + nt, lane, a2);
    float bo = bih[1792 + j] + bhh[1792 + j];
    #pragma unroll
    for (int mt = 0; mt < 2; ++mt)
      #pragma unroll
      for (int r = 0; r < 4; ++r){
        int m = mt * 16 + rsub + r;
        int ofs = m * 256 + (j ^ ((m & 7) << 3));
        float c1v = bf2f(s_b[ofs]);
        s_b[ofs] = f2bf(sigm(a2[mt][r] + bo) * tanh_(c1v));
      }
  }
  __syncthreads();

  // ======== HS mix (s_h own slots) + MID1 (m1 -> regs)
  uint32_t m1p[4][2][2];
  #pragma unroll
  for (int t = 0; t < 4; ++t){
    int nt = w * 4 + t, j = w * 64 + t * 16 + jl;
    f32x4 ah[2] = {};
    gemm1(s_b, pk + OFF_HS, nt, lane, ah);
    float hb = hsb[j];
    #pragma unroll
    for (int mt = 0; mt < 2; ++mt)
      #pragma unroll
      for (int r = 0; r < 4; ++r){
        int m = mt * 16 + rsub + r;
        int ofs = m * 256 + (j ^ ((m & 7) << 3));
        s_h[ofs] = f2bf(bf2f(s_h[ofs]) + ah[mt][r] + hb);
      }
    f32x4 am[2] = {};
    gemm1(s_b, pk + OFF_MID + 65536, nt, lane, am);
    float mb = midb[256 + j];
    #pragma unroll
    for (int mt = 0; mt < 2; ++mt){
      float v0 = am[mt][0] + mb; v0 = v0 > 0.f ? v0 : 0.f;
      float v1 = am[mt][1] + mb; v1 = v1 > 0.f ? v1 : 0.f;
      float v2 = am[mt][2] + mb; v2 = v2 > 0.f ? v2 : 0.f;
      float v3 = am[mt][3] + mb; v3 = v3 > 0.f ? v3 : 0.f;
      m1p[t][mt][0] = pk2(v0, v1);
      m1p[t][mt][1] = pk2(v2, v3);
    }
  }
  __syncthreads();

  // m1 -> s_b
  #pragma unroll
  for (int t = 0; t < 4; ++t){
    int j = w * 64 + t * 16 + jl;
    #pragma unroll
    for (int mt = 0; mt < 2; ++mt)
      #pragma unroll
      for (int pr = 0; pr < 2; ++pr){
        uint32_t u = m1p[t][mt][pr];
        int m0 = mt * 16 + rsub + 2 * pr;
        s_b[m0 * 256 + (j ^ ((m0 & 7) << 3))] = (unsigned short)(u & 0xFFFF);
        int m1 = m0 + 1;
        s_b[m1 * 256 + (j ^ ((m1 & 7) << 3))] = (unsigned short)(u >> 16);
      }
  }
  __syncthreads();

  // ======== OUT1 (23 cols)
  {
    f32x4 ao1 = {0.f, 0.f, 0.f, 0.f};
    gemm1q(s_b, pk + OFF_OUT1, w & 1, w >> 1, lane, ao1);
    __syncthreads();
    float* s_of = (float*)s_b;
    int colc = (w & 1) * 16 + jl;
    if (colc < 23){
      float ob = ob1[colc];
      #pragma unroll
      for (int r = 0; r < 4; ++r){
        int m = (w >> 1) * 16 + rsub + r;
        s_of[m * 23 + colc] = ao1[r] + ob;
      }
    }
    __syncthreads();
    float4* op = (float4*)(out + 3538944 + (size_t)row0 * 23);
    const float4* s4 = (const float4*)s_of;
    for (int e = tid; e < 184; e += 256) op[e] = s4[e];
  }
  __syncthreads();

  // ======== STAGE2: i,f,g,o inline (cc in c0p; c2 in f32 locals); h2 -> s_b
  #pragma unroll
  for (int t = 0; t < 4; ++t){
    int nt = w * 4 + t, j = w * 64 + t * 16 + jl;
    uint32_t sip[2][2], sfp[2][2];
    {
      f32x4 a2[2] = {};
      gemm1(s_x, pk + OFF_WIH + 524288, nt, lane, a2);
      gemm1(s_h, pk + OFF_WHH + 262144, nt, lane, a2);
      float bi = bih[2048 + j] + bhh[2048 + j];
      #pragma unroll
      for (int mt = 0; mt < 2; ++mt){
        sip[mt][0] = pk2(sigm(a2[mt][0] + bi), sigm(a2[mt][1] + bi));
        sip[mt][1] = pk2(sigm(a2[mt][2] + bi), sigm(a2[mt][3] + bi));
      }
    }
    {
      f32x4 a2[2] = {};
      gemm1(s_x, pk + OFF_WIH + 524288, 16 + nt, lane, a2);
      gemm1(s_h, pk + OFF_WHH + 262144, 16 + nt, lane, a2);
      float bf_ = bih[2304 + j] + bhh[2304 + j];
      #pragma unroll
      for (int mt = 0; mt < 2; ++mt){
        sfp[mt][0] = pk2(sigm(a2[mt][0] + bf_), sigm(a2[mt][1] + bf_));
        sfp[mt][1] = pk2(sigm(a2[mt][2] + bf_), sigm(a2[mt][3] + bf_));
      }
    }
    uint32_t c2p[2][2];
    {
      f32x4 a2[2] = {};
      gemm1(s_x, pk + OFF_WIH + 524288, 32 + nt, lane, a2);
      gemm1(s_h, pk + OFF_WHH + 262144, 32 + nt, lane, a2);
      float bg = bih[2560 + j] + bhh[2560 + j];
      #pragma unroll
      for (int mt = 0; mt < 2; ++mt){
        float cv[4];
        #pragma unroll
        for (int r = 0; r < 4; ++r)
          cv[r] = upk(sfp[mt][r >> 1], r & 1) * upk(c0p[t][mt][r >> 1], r & 1)
                + upk(sip[mt][r >> 1], r & 1) * tanh_(a2[mt][r] + bg);
        c2p[mt][0] = pk2(cv[0], cv[1]);
        c2p[mt][1] = pk2(cv[2], cv[3]);
      }
    }
    {
      f32x4 a2[2] = {};
      gemm1(s_x, pk + OFF_WIH + 524288, 48 + nt, lane, a2);
      gemm1(s_h, pk + OFF_WHH + 262144, 48 + nt, lane, a2);
      float bo = bih[2816 + j] + bhh[2816 + j];
      #pragma unroll
      for (int mt = 0; mt < 2; ++mt)
        #pragma unroll
        for (int r = 0; r < 4; ++r){
          float h2 = sigm(a2[mt][r] + bo) * tanh_(upk(c2p[mt][r >> 1], r & 1));
          int m = mt * 16 + rsub + r;
          s_b[m * 256 + (j ^ ((m & 7) << 3))] = f2bf(h2);
        }
    }
  }
  __syncthreads();

  // ======== MID2 (from s_b=h2) -> regs -> s_b
  #pragma unroll
  for (int t = 0; t < 4; ++t){
    int nt = w * 4 + t, j = w * 64 + t * 16 + jl;
    f32x4 am[2] = {};
    gemm1(s_b, pk + OFF_MID + 131072, nt, lane, am);
    float mb = midb[512 + j];
    #pragma unroll
    for (int mt = 0; mt < 2; ++mt){
      float v0 = am[mt][0] + mb; v0 = v0 > 0.f ? v0 : 0.f;
      float v1 = am[mt][1] + mb; v1 = v1 > 0.f ? v1 : 0.f;
      float v2 = am[mt][2] + mb; v2 = v2 > 0.f ? v2 : 0.f;
      float v3 = am[mt][3] + mb; v3 = v3 > 0.f ? v3 : 0.f;
      m1p[t][mt][0] = pk2(v0, v1);
      m1p[t][mt][1] = pk2(v2, v3);
    }
  }
  __syncthreads();
  #pragma unroll
  for (int t = 0; t < 4; ++t){
    int j = w * 64 + t * 16 + jl;
    #pragma unroll
    for (int mt = 0; mt < 2; ++mt)
      #pragma unroll
      for (int pr = 0; pr < 2; ++pr){
        uint32_t u = m1p[t][mt][pr];
        int m0 = mt * 16 + rsub + 2 * pr;
        s_b[m0 * 256 + (j ^ ((m0 & 7) << 3))] = (unsigned short)(u & 0xFFFF);
        int m1 = m0 + 1;
        s_b[m1 * 256 + (j ^ ((m1 & 7) << 3))] = (unsigned short)(u >> 16);
      }
  }
  __syncthreads();

  // ======== OUT2 (20 cols)
  {
    f32x4 ao2 = {0.f, 0.f, 0.f, 0.f};
    gemm1q(s_b, pk + OFF_OUT2, w & 1, w >> 1, lane, ao2);
    __syncthreads();
    float* s_of = (float*)s_b;
    int colc = (w & 1) * 16 + jl;
    if (colc < 20){
      float ob = ob2[colc];
      #pragma unroll
      for (int r = 0; r < 4; ++r){
        int m = (w >> 1) * 16 + rsub + r;
        s_of[m * 20 + colc] = ao2[r] + ob;
      }
    }
    __syncthreads();
    float4* op = (float4*)(out + 5046272 + (size_t)row0 * 20);
    const float4* s4 = (const float4*)s_of;
    for (int e = tid; e < 160; e += 256) op[e] = s4[e];
  }
}

extern "C" void kernel_launch(void* const* d_in, const int* in_sizes, int n_in,
                              void* d_out, int out_size, void* d_ws, size_t ws_size,
                              hipStream_t stream)
{
  const float* x     = (const float*)d_in[0];
  const float* Wih   = (const float*)d_in[1];
  const float* Whh   = (const float*)d_in[2];
  const float* bih   = (const float*)d_in[3];
  const float* bhh   = (const float*)d_in[4];
  const float* hsW   = (const float*)d_in[5];
  const float* hsb   = (const float*)d_in[6];
  const float* csW   = (const float*)d_in[7];
  const float* csb   = (const float*)d_in[8];
  const float* midW  = (const float*)d_in[9];
  const float* midb  = (const float*)d_in[10];
  const float* outW0 = (const float*)d_in[11];
  const float* outb0 = (const float*)d_in[12];
  const float* outW1 = (const float*)d_in[13];
  const float* outb1 = (const float*)d_in[14];
  const float* outW2 = (const float*)d_in[15];
  const float* outb2 = (const float*)d_in[16];

  unsigned short* pk = (unsigned short*)d_ws;

  int ngroups = PK_TOTAL / 8;
  pack_all<<<(ngroups + 255) / 256, 256, 0, stream>>>(
      Wih, Whh, hsW + 5 * 65536, csW + 5 * 65536, midW, outW0, outW1, outW2, pk);

  lstm_fused<<<2048, 256, 0, stream>>>(
      x, pk, bih, bhh, hsb + 5 * 256, csb + 5 * 256, midb,
      outb0, outb1, outb2, (float*)d_out);
}

// Round 15
// 432.479 us; speedup vs baseline: 2.7625x; 1.7023x over previous
//
#include <hip/hip_runtime.h>
#include <stdint.h>

// ============================================================================
// LSTMDecoder fused — MI355X/gfx950 — R15: R14 fragment-order LDS, OOB fixed
//
// R14 crashed: stage-1 Wih tile pointer computed (32768+nt)*512 (~8.5 GB OOB)
// instead of (64+nt)*512. Single-line fix; design unchanged:
// LDS A-tiles in MFMA fragment order [mt][kc][lane][8] -> reads are
// ds_read_b128 at base+lane*16+const (0 VALU, linear = conflict-free);
// bih+bhh pre-summed in prepass. R11 structure: 32 rows/WG, 2048 WGs,
// (256,2) -> 128 VGPR, 64 KiB LDS -> 2 WG/CU, 8 waves, indep clocks.
// ============================================================================

typedef __attribute__((ext_vector_type(8))) short bf16x8;
typedef __attribute__((ext_vector_type(4))) float f32x4;

#define OFF_WIH  0         // 3 x 64 tiles (i:0-15 f:16-31 g:32-47 o:48-63)
#define OFF_WHH  786432    // 2 x 64 tiles (a=1,2)
#define OFF_HS   1310720   // 16 tiles
#define OFF_CS   1376256   // 16 tiles
#define OFF_MID  1441792   // 3 x 16 tiles
#define OFF_OUT0 1638400   // 4 tiles
#define OFF_OUT1 1654784   // 2 tiles
#define OFF_OUT2 1662976   // 2 tiles
#define PK_TOTAL 1671168   // weight elems; bias f32[3072] appended after

__device__ __forceinline__ unsigned short f2bf(float f){
  uint32_t u = __float_as_uint(f);
  u += 0x7FFFu + ((u >> 16) & 1u);
  return (unsigned short)(u >> 16);
}
__device__ __forceinline__ float bf2f(unsigned short h){
  return __uint_as_float(((uint32_t)h) << 16);
}
__device__ __forceinline__ float sigm(float x){
  return __builtin_amdgcn_rcpf(1.0f + __expf(-x));
}
__device__ __forceinline__ float tanh_(float x){
  return 2.0f * __builtin_amdgcn_rcpf(1.0f + __expf(-2.0f * x)) - 1.0f;
}

// fragment-order offset of element (row m, col j) in a 32x256 tile
__device__ __forceinline__ int fofs(int m, int j){
  return ((((m >> 4) << 3) + (j >> 5)) << 9)
       + ((((j >> 3) & 3) << 4) + (m & 15)) * 8 + (j & 7);
}

// ---------------------------------------------------------------------------
// Prepass: weights (f32 [N][256]) -> bf16 MFMA-B fragment order; then
// combined bias table bsum = bih + bhh (f32[3072]) appended after weights.
// ---------------------------------------------------------------------------
__global__ __launch_bounds__(256)
void pack_all(const float* __restrict__ Wih, const float* __restrict__ Whh,
              const float* __restrict__ hsW, const float* __restrict__ csW,
              const float* __restrict__ midW,
              const float* __restrict__ oW0, const float* __restrict__ oW1,
              const float* __restrict__ oW2,
              const float* __restrict__ bih, const float* __restrict__ bhh,
              unsigned short* __restrict__ pk)
{
  int g = blockIdx.x * 256 + threadIdx.x;
  const int NW = PK_TOTAL / 8;
  if (g >= NW){
    int g2 = g - NW;
    if (g2 < 384){
      float* bs = (float*)(pk + PK_TOTAL);
      #pragma unroll
      for (int i = 0; i < 8; ++i){
        int idx = g2 * 8 + i;                 // [a][gate][256] flat = 3072
        bs[idx] = bih[idx] + bhh[idx];
      }
    }
    return;
  }
  int tile = g >> 9;
  int within = g & 511;
  int lane = within & 63;
  int kc = within >> 6;

  const float* s; int nt_local, Nsrc;
  if      (tile < 192){ int a = tile / 64; nt_local = tile % 64; s = Wih + (size_t)a * 262144; Nsrc = 1024; }
  else if (tile < 320){ int a = 1 + (tile - 192) / 64; nt_local = (tile - 192) % 64; s = Whh + (size_t)a * 262144; Nsrc = 1024; }
  else if (tile < 336){ nt_local = tile - 320; s = hsW; Nsrc = 256; }
  else if (tile < 352){ nt_local = tile - 336; s = csW; Nsrc = 256; }
  else if (tile < 400){ int a = (tile - 352) / 16; nt_local = (tile - 352) % 16; s = midW + a * 65536; Nsrc = 256; }
  else if (tile < 404){ nt_local = tile - 400; s = oW0; Nsrc = 54; }
  else if (tile < 406){ nt_local = tile - 404; s = oW1; Nsrc = 23; }
  else                { nt_local = tile - 406; s = oW2; Nsrc = 20; }

  int n = nt_local * 16 + (lane & 15);
  int k = kc * 32 + ((lane >> 4) << 3);
  bf16x8 bv;
  if (n < Nsrc){
    const float* sp = s + (size_t)n * 256 + k;
    #pragma unroll
    for (int i = 0; i < 8; ++i) bv[i] = (short)f2bf(sp[i]);
  } else {
    #pragma unroll
    for (int i = 0; i < 8; ++i) bv[i] = 0;
  }
  *(bf16x8*)(pk + (size_t)g * 8) = bv;
}

// ---------------------------------------------------------------------------
// GEMM passes. A: fragment-order LDS tile, sAl = tile_base + lane*8.
// B: Bl = (bf16x8*)(pk+OFF) + tile*512 + lane. Lane holds D[(l>>4)*4+r][l&15].

__device__ __forceinline__ void gate_gemm(const unsigned short* sAl, const bf16x8* Bl,
                                          f32x4 (&acc)[2][4])
{
  #pragma unroll
  for (int kc = 0; kc < 8; ++kc){
    bf16x8 b0 = Bl[kc * 64];
    bf16x8 b1 = Bl[16 * 512 + kc * 64];
    bf16x8 b2 = Bl[32 * 512 + kc * 64];
    bf16x8 b3 = Bl[48 * 512 + kc * 64];
    #pragma unroll
    for (int mt = 0; mt < 2; ++mt){
      bf16x8 a = *(const bf16x8*)(sAl + (mt * 8 + kc) * 512);
      acc[mt][0] = __builtin_amdgcn_mfma_f32_16x16x32_bf16(a, b0, acc[mt][0], 0, 0, 0);
      acc[mt][1] = __builtin_amdgcn_mfma_f32_16x16x32_bf16(a, b1, acc[mt][1], 0, 0, 0);
      acc[mt][2] = __builtin_amdgcn_mfma_f32_16x16x32_bf16(a, b2, acc[mt][2], 0, 0, 0);
      acc[mt][3] = __builtin_amdgcn_mfma_f32_16x16x32_bf16(a, b3, acc[mt][3], 0, 0, 0);
    }
  }
}

// stage-0 variant: f-gate dead -> i (tile+0), g (+32), o (+48)
__device__ __forceinline__ void gate_gemm3(const unsigned short* sAl, const bf16x8* Bl,
                                           f32x4 (&acc)[2][3])
{
  #pragma unroll
  for (int kc = 0; kc < 8; ++kc){
    bf16x8 b0 = Bl[kc * 64];
    bf16x8 b2 = Bl[32 * 512 + kc * 64];
    bf16x8 b3 = Bl[48 * 512 + kc * 64];
    #pragma unroll
    for (int mt = 0; mt < 2; ++mt){
      bf16x8 a = *(const bf16x8*)(sAl + (mt * 8 + kc) * 512);
      acc[mt][0] = __builtin_amdgcn_mfma_f32_16x16x32_bf16(a, b0, acc[mt][0], 0, 0, 0);
      acc[mt][1] = __builtin_amdgcn_mfma_f32_16x16x32_bf16(a, b2, acc[mt][1], 0, 0, 0);
      acc[mt][2] = __builtin_amdgcn_mfma_f32_16x16x32_bf16(a, b3, acc[mt][2], 0, 0, 0);
    }
  }
}

__device__ __forceinline__ void gemm1(const unsigned short* sAl, const bf16x8* Bl,
                                      f32x4 (&acc)[2])
{
  #pragma unroll
  for (int kc = 0; kc < 8; ++kc){
    bf16x8 b = Bl[kc * 64];
    #pragma unroll
    for (int mt = 0; mt < 2; ++mt){
      bf16x8 a = *(const bf16x8*)(sAl + (mt * 8 + kc) * 512);
      acc[mt] = __builtin_amdgcn_mfma_f32_16x16x32_bf16(a, b, acc[mt], 0, 0, 0);
    }
  }
}

// single 16-row block mh (0/1)
__device__ __forceinline__ void gemm1q(const unsigned short* sAl, const bf16x8* Bl,
                                       int mh, f32x4 &acc)
{
  #pragma unroll
  for (int kc = 0; kc < 8; ++kc){
    bf16x8 b = Bl[kc * 64];
    bf16x8 a = *(const bf16x8*)(sAl + (mh * 8 + kc) * 512);
    acc = __builtin_amdgcn_mfma_f32_16x16x32_bf16(a, b, acc, 0, 0, 0);
  }
}

// ---------------------------------------------------------------------------
__global__ __launch_bounds__(256, 2)
void lstm_fused(const float* __restrict__ x, const unsigned short* __restrict__ pk,
                const float* __restrict__ hsb, const float* __restrict__ csb,
                const float* __restrict__ midb,
                const float* __restrict__ ob0, const float* __restrict__ ob1,
                const float* __restrict__ ob2, float* __restrict__ out)
{
  __shared__ __align__(16) unsigned short smem[32768];   // 64 KiB -> 2 WG/CU
  unsigned short* s_x  = smem;            // frag-order x
  unsigned short* s_h0 = smem + 8192;     // h0 -> hh
  unsigned short* s_h1 = smem + 16384;    // h1 -> h2
  unsigned short* s_bu = smem + 24576;    // m/c1 frag-order; f32 out staging

  const int tid  = threadIdx.x;
  const int lane = tid & 63;
  const int w    = tid >> 6;              // col quarter 0..3
  const int row0 = blockIdx.x * 32;
  const int rsub = (lane >> 4) << 2;
  const int jl   = lane & 15;

  const float* bsum = (const float*)(pk + PK_TOTAL);

  const unsigned short* sxl = s_x  + lane * 8;
  const unsigned short* shl = s_h0 + lane * 8;
  const unsigned short* s1l = s_h1 + lane * 8;
  const unsigned short* sbl = s_bu + lane * 8;
  const bf16x8* Bwih = (const bf16x8*)(pk + OFF_WIH) + lane;
  const bf16x8* Bwhh = (const bf16x8*)(pk + OFF_WHH) + lane;
  const bf16x8* Bhs  = (const bf16x8*)(pk + OFF_HS)  + lane;
  const bf16x8* Bcs  = (const bf16x8*)(pk + OFF_CS)  + lane;
  const bf16x8* Bmid = (const bf16x8*)(pk + OFF_MID) + lane;
  const bf16x8* Bo0  = (const bf16x8*)(pk + OFF_OUT0) + lane;
  const bf16x8* Bo1  = (const bf16x8*)(pk + OFF_OUT1) + lane;
  const bf16x8* Bo2  = (const bf16x8*)(pk + OFF_OUT2) + lane;

  // ---- stage x: f32 -> bf16, fragment order
  {
    const float* xg = x + (size_t)row0 * 256;
    #pragma unroll
    for (int it = 0; it < 4; ++it){
      int idx = it * 2048 + tid * 8;
      int row = idx >> 8, col = idx & 255;
      float4 v0 = *(const float4*)(xg + idx);
      float4 v1 = *(const float4*)(xg + idx + 4);
      bf16x8 bv;
      bv[0]=(short)f2bf(v0.x); bv[1]=(short)f2bf(v0.y); bv[2]=(short)f2bf(v0.z); bv[3]=(short)f2bf(v0.w);
      bv[4]=(short)f2bf(v1.x); bv[5]=(short)f2bf(v1.y); bv[6]=(short)f2bf(v1.z); bv[7]=(short)f2bf(v1.w);
      *(bf16x8*)(s_x + fofs(row, col)) = bv;   // col 8-aligned -> b128 store
    }
  }
  __syncthreads();

  float c0[4][2][4];   // c-state in regs: [t][mt][r]

  // ======== STAGE 0: gates i,g,o from x (f dead)
  #pragma unroll
  for (int t = 0; t < 4; ++t){
    int nt = w * 4 + t, j = w * 64 + t * 16 + jl;
    f32x4 acc[2][3] = {};
    gate_gemm3(sxl, Bwih + nt * 512, acc);
    float bi = bsum[j];
    float bg = bsum[512 + j];
    float bo = bsum[768 + j];
    #pragma unroll
    for (int mt = 0; mt < 2; ++mt){
      #pragma unroll
      for (int r = 0; r < 4; ++r){
        float c = sigm(acc[mt][0][r] + bi) * tanh_(acc[mt][1][r] + bg);
        float h = sigm(acc[mt][2][r] + bo) * tanh_(c);
        c0[t][mt][r] = c;
        int m = mt * 16 + rsub + r;
        s_h0[fofs(m, j)] = f2bf(h);
      }
    }
  }
  __syncthreads();

  // ======== MID0
  #pragma unroll
  for (int t = 0; t < 4; ++t){
    int nt = w * 4 + t, j = w * 64 + t * 16 + jl;
    f32x4 am[2] = {};
    gemm1(shl, Bmid + nt * 512, am);
    float mb = midb[j];
    #pragma unroll
    for (int mt = 0; mt < 2; ++mt)
      #pragma unroll
      for (int r = 0; r < 4; ++r){
        float v = am[mt][r] + mb; v = v > 0.f ? v : 0.f;
        int m = mt * 16 + rsub + r;
        s_bu[fofs(m, j)] = f2bf(v);
      }
  }
  __syncthreads();

  // ======== OUT0 (54 cols): wave w -> nt=w
  {
    f32x4 ao2[2] = {};
    gemm1(sbl, Bo0 + w * 512, ao2);
    __syncthreads();
    float* s_of = (float*)s_bu;
    int colc = w * 16 + jl;
    if (colc < 54){
      float ob = ob0[colc];
      #pragma unroll
      for (int mt = 0; mt < 2; ++mt)
        #pragma unroll
        for (int r = 0; r < 4; ++r){
          int m = mt * 16 + rsub + r;
          s_of[m * 54 + colc] = ao2[mt][r] + ob;
        }
    }
    __syncthreads();
    float4* op = (float4*)(out + (size_t)row0 * 54);
    const float4* s4 = (const float4*)s_of;
    for (int e = tid; e < 432; e += 256) op[e] = s4[e];
  }
  __syncthreads();

  // ======== STAGE 1: all 4 gates; uses c0
  #pragma unroll
  for (int t = 0; t < 4; ++t){
    int nt = w * 4 + t, j = w * 64 + t * 16 + jl;
    f32x4 acc[2][4] = {};
    gate_gemm(sxl, Bwih + (64 + nt) * 512, acc);   // a=1 Wih tiles 64..127
    gate_gemm(shl, Bwhh + nt * 512, acc);
    float bi = bsum[1024 + j];
    float bf_= bsum[1280 + j];
    float bg = bsum[1536 + j];
    float bo = bsum[1792 + j];
    #pragma unroll
    for (int mt = 0; mt < 2; ++mt){
      #pragma unroll
      for (int r = 0; r < 4; ++r){
        float c1 = sigm(acc[mt][1][r] + bf_) * c0[t][mt][r]
                 + sigm(acc[mt][0][r] + bi ) * tanh_(acc[mt][2][r] + bg);
        float h1 = sigm(acc[mt][3][r] + bo) * tanh_(c1);
        int m = mt * 16 + rsub + r;
        int ofs = fofs(m, j);
        s_h1[ofs] = f2bf(h1);
        s_bu[ofs] = f2bf(c1);
      }
    }
  }
  __syncthreads();

  // ======== HS/CS mix: hh = h0 + h1*hsW^T + hsb (in place); cc into c0
  #pragma unroll
  for (int t = 0; t < 4; ++t){
    int nt = w * 4 + t, j = w * 64 + t * 16 + jl;
    f32x4 ah[2] = {}, ac[2] = {};
    gemm1(s1l, Bhs + nt * 512, ah);
    gemm1(sbl, Bcs + nt * 512, ac);
    float hb = hsb[j], cb = csb[j];
    #pragma unroll
    for (int mt = 0; mt < 2; ++mt){
      #pragma unroll
      for (int r = 0; r < 4; ++r){
        int m = mt * 16 + rsub + r;
        int ofs = fofs(m, j);
        float hh = bf2f(s_h0[ofs]) + ah[mt][r] + hb;   // own slot: no race
        s_h0[ofs] = f2bf(hh);
        c0[t][mt][r] += ac[mt][r] + cb;
      }
    }
  }
  __syncthreads();

  // ======== MID1
  #pragma unroll
  for (int t = 0; t < 4; ++t){
    int nt = w * 4 + t, j = w * 64 + t * 16 + jl;
    f32x4 am[2] = {};
    gemm1(s1l, Bmid + (16 + nt) * 512, am);
    float mb = midb[256 + j];
    #pragma unroll
    for (int mt = 0; mt < 2; ++mt)
      #pragma unroll
      for (int r = 0; r < 4; ++r){
        float v = am[mt][r] + mb; v = v > 0.f ? v : 0.f;
        int m = mt * 16 + rsub + r;
        s_bu[fofs(m, j)] = f2bf(v);
      }
  }
  __syncthreads();

  // ======== OUT1 (23 cols): nt=w&1, 16-row half mh=w>>1
  {
    f32x4 ao1 = {0.f, 0.f, 0.f, 0.f};
    gemm1q(sbl, Bo1 + (w & 1) * 512, w >> 1, ao1);
    __syncthreads();
    float* s_of = (float*)s_bu;
    int colc = (w & 1) * 16 + jl;
    if (colc < 23){
      float ob = ob1[colc];
      #pragma unroll
      for (int r = 0; r < 4; ++r){
        int m = (w >> 1) * 16 + rsub + r;
        s_of[m * 23 + colc] = ao1[r] + ob;
      }
    }
    __syncthreads();
    float4* op = (float4*)(out + 3538944 + (size_t)row0 * 23);
    const float4* s4 = (const float4*)s_of;
    for (int e = tid; e < 184; e += 256) op[e] = s4[e];
  }
  __syncthreads();

  // ======== STAGE 2: all 4 gates; uses cc (in c0)
  #pragma unroll
  for (int t = 0; t < 4; ++t){
    int nt = w * 4 + t, j = w * 64 + t * 16 + jl;
    f32x4 acc[2][4] = {};
    gate_gemm(sxl, Bwih + (128 + nt) * 512, acc);  // a=2 Wih tiles 128..191
    gate_gemm(shl, Bwhh + (64 + nt) * 512, acc);   // a=2 Whh tiles 64..127
    float bi = bsum[2048 + j];
    float bf_= bsum[2304 + j];
    float bg = bsum[2560 + j];
    float bo = bsum[2816 + j];
    #pragma unroll
    for (int mt = 0; mt < 2; ++mt){
      #pragma unroll
      for (int r = 0; r < 4; ++r){
        float c2 = sigm(acc[mt][1][r] + bf_) * c0[t][mt][r]
                 + sigm(acc[mt][0][r] + bi ) * tanh_(acc[mt][2][r] + bg);
        float h2 = sigm(acc[mt][3][r] + bo) * tanh_(c2);
        int m = mt * 16 + rsub + r;
        s_h1[fofs(m, j)] = f2bf(h2);
      }
    }
  }
  __syncthreads();

  // ======== MID2
  #pragma unroll
  for (int t = 0; t < 4; ++t){
    int nt = w * 4 + t, j = w * 64 + t * 16 + jl;
    f32x4 am[2] = {};
    gemm1(s1l, Bmid + (32 + nt) * 512, am);
    float mb = midb[512 + j];
    #pragma unroll
    for (int mt = 0; mt < 2; ++mt)
      #pragma unroll
      for (int r = 0; r < 4; ++r){
        float v = am[mt][r] + mb; v = v > 0.f ? v : 0.f;
        int m = mt * 16 + rsub + r;
        s_bu[fofs(m, j)] = f2bf(v);
      }
  }
  __syncthreads();

  // ======== OUT2 (20 cols)
  {
    f32x4 ao2 = {0.f, 0.f, 0.f, 0.f};
    gemm1q(sbl, Bo2 + (w & 1) * 512, w >> 1, ao2);
    __syncthreads();
    float* s_of = (float*)s_bu;
    int colc = (w & 1) * 16 + jl;
    if (colc < 20){
      float ob = ob2[colc];
      #pragma unroll
      for (int r = 0; r < 4; ++r){
        int m = (w >> 1) * 16 + rsub + r;
        s_of[m * 20 + colc] = ao2[r] + ob;
      }
    }
    __syncthreads();
    float4* op = (float4*)(out + 5046272 + (size_t)row0 * 20);
    const float4* s4 = (const float4*)s_of;
    for (int e = tid; e < 160; e += 256) op[e] = s4[e];
  }
}

extern "C" void kernel_launch(void* const* d_in, const int* in_sizes, int n_in,
                              void* d_out, int out_size, void* d_ws, size_t ws_size,
                              hipStream_t stream)
{
  const float* x     = (const float*)d_in[0];
  const float* Wih   = (const float*)d_in[1];
  const float* Whh   = (const float*)d_in[2];
  const float* bih   = (const float*)d_in[3];
  const float* bhh   = (const float*)d_in[4];
  const float* hsW   = (const float*)d_in[5];
  const float* hsb   = (const float*)d_in[6];
  const float* csW   = (const float*)d_in[7];
  const float* csb   = (const float*)d_in[8];
  const float* midW  = (const float*)d_in[9];
  const float* midb  = (const float*)d_in[10];
  const float* outW0 = (const float*)d_in[11];
  const float* outb0 = (const float*)d_in[12];
  const float* outW1 = (const float*)d_in[13];
  const float* outb1 = (const float*)d_in[14];
  const float* outW2 = (const float*)d_in[15];
  const float* outb2 = (const float*)d_in[16];

  unsigned short* pk = (unsigned short*)d_ws;

  int ngroups = PK_TOTAL / 8 + 384;     // weights + bias table
  pack_all<<<(ngroups + 255) / 256, 256, 0, stream>>>(
      Wih, Whh, hsW + 5 * 65536, csW + 5 * 65536, midW, outW0, outW1, outW2,
      bih, bhh, pk);

  lstm_fused<<<2048, 256, 0, stream>>>(
      x, pk, hsb + 5 * 256, csb + 5 * 256, midb,
      outb0, outb1, outb2, (float*)d_out);
}

// Round 16
// 280.569 us; speedup vs baseline: 4.2582x; 1.5414x over previous
//
#include <hip/hip_runtime.h>
#include <stdint.h>

// ============================================================================
// LSTMDecoder fused — MI355X/gfx950 — R16: R11 layout + s_setprio on MFMA
//
// R11 = 398us frontier. R12-R15 lessons: 84-reg regime spills (x2), fewer
// VALU/conflicts don't help (R15: VALU 39->21%, conflicts /3.3, dur +5%) —
// the kernel is latency-bound on ~99 barrier-separated L2-B-load GEMM passes
// at 2 waves/SIMD. Untried lever: T5 s_setprio. Prereq (wave role diversity)
// holds: 2 INDEPENDENT WGs/CU on separate barrier clocks. Wrap each GEMM
// pass in setprio(1)/(0) so MFMA-entering waves preempt the other WG's
// load/barrier waves. Everything else is R11 verbatim.
// ============================================================================

typedef __attribute__((ext_vector_type(8))) short bf16x8;
typedef __attribute__((ext_vector_type(4))) float f32x4;

#define OFF_WIH  0
#define OFF_WHH  786432
#define OFF_HS   1310720
#define OFF_CS   1376256
#define OFF_MID  1441792
#define OFF_OUT0 1638400
#define OFF_OUT1 1654784
#define OFF_OUT2 1662976
#define PK_TOTAL 1671168

__device__ __forceinline__ unsigned short f2bf(float f){
  uint32_t u = __float_as_uint(f);
  u += 0x7FFFu + ((u >> 16) & 1u);
  return (unsigned short)(u >> 16);
}
__device__ __forceinline__ float bf2f(unsigned short h){
  return __uint_as_float(((uint32_t)h) << 16);
}
__device__ __forceinline__ float sigm(float x){
  return __builtin_amdgcn_rcpf(1.0f + __expf(-x));
}
__device__ __forceinline__ float tanh_(float x){
  return 2.0f * __builtin_amdgcn_rcpf(1.0f + __expf(-2.0f * x)) - 1.0f;
}

// ---------------------------------------------------------------------------
__global__ __launch_bounds__(256)
void pack_all(const float* __restrict__ Wih, const float* __restrict__ Whh,
              const float* __restrict__ hsW, const float* __restrict__ csW,
              const float* __restrict__ midW,
              const float* __restrict__ oW0, const float* __restrict__ oW1,
              const float* __restrict__ oW2,
              unsigned short* __restrict__ pk)
{
  int g = blockIdx.x * 256 + threadIdx.x;
  if (g >= PK_TOTAL / 8) return;
  int tile = g >> 9;
  int within = g & 511;
  int lane = within & 63;
  int kc = within >> 6;

  const float* s; int nt_local, Nsrc;
  if      (tile < 192){ int a = tile / 64; nt_local = tile % 64; s = Wih + (size_t)a * 262144; Nsrc = 1024; }
  else if (tile < 320){ int a = 1 + (tile - 192) / 64; nt_local = (tile - 192) % 64; s = Whh + (size_t)a * 262144; Nsrc = 1024; }
  else if (tile < 336){ nt_local = tile - 320; s = hsW; Nsrc = 256; }
  else if (tile < 352){ nt_local = tile - 336; s = csW; Nsrc = 256; }
  else if (tile < 400){ int a = (tile - 352) / 16; nt_local = (tile - 352) % 16; s = midW + a * 65536; Nsrc = 256; }
  else if (tile < 404){ nt_local = tile - 400; s = oW0; Nsrc = 54; }
  else if (tile < 406){ nt_local = tile - 404; s = oW1; Nsrc = 23; }
  else                { nt_local = tile - 406; s = oW2; Nsrc = 20; }

  int n = nt_local * 16 + (lane & 15);
  int k = kc * 32 + ((lane >> 4) << 3);
  bf16x8 bv;
  if (n < Nsrc){
    const float* sp = s + (size_t)n * 256 + k;
    #pragma unroll
    for (int i = 0; i < 8; ++i) bv[i] = (short)f2bf(sp[i]);
  } else {
    #pragma unroll
    for (int i = 0; i < 8; ++i) bv[i] = 0;
  }
  *(bf16x8*)(pk + (size_t)g * 8) = bv;
}

// ---------------------------------------------------------------------------
// GEMM helpers (R11 layout). A: LDS [32 rows][256 k] bf16, XOR-swizzled
// ((row&7)<<3). B: packed frags. Lane holds D[(l>>4)*4+r][l&15].
// Each pass wrapped in s_setprio(1)/(0) — T5.
// ---------------------------------------------------------------------------
__device__ __forceinline__ void gate_gemm(const unsigned short* sA, const unsigned short* pkB,
                                          int nt0, int lane, f32x4 (&acc)[2][4])
{
  const bf16x8* B = (const bf16x8*)pkB;
  const int g16  = (lane >> 4) << 3;
  const int swz  = (lane & 7) << 3;
  const int rbase = lane & 15;
  __builtin_amdgcn_s_setprio(1);
  #pragma unroll
  for (int kc = 0; kc < 8; ++kc){
    bf16x8 b0 = B[(nt0     ) * 512 + kc * 64 + lane];
    bf16x8 b1 = B[(nt0 + 16) * 512 + kc * 64 + lane];
    bf16x8 b2 = B[(nt0 + 32) * 512 + kc * 64 + lane];
    bf16x8 b3 = B[(nt0 + 48) * 512 + kc * 64 + lane];
    int kcol = (kc * 32 + g16) ^ swz;
    #pragma unroll
    for (int mt = 0; mt < 2; ++mt){
      bf16x8 a = *(const bf16x8*)(sA + (mt * 16 + rbase) * 256 + kcol);
      acc[mt][0] = __builtin_amdgcn_mfma_f32_16x16x32_bf16(a, b0, acc[mt][0], 0, 0, 0);
      acc[mt][1] = __builtin_amdgcn_mfma_f32_16x16x32_bf16(a, b1, acc[mt][1], 0, 0, 0);
      acc[mt][2] = __builtin_amdgcn_mfma_f32_16x16x32_bf16(a, b2, acc[mt][2], 0, 0, 0);
      acc[mt][3] = __builtin_amdgcn_mfma_f32_16x16x32_bf16(a, b3, acc[mt][3], 0, 0, 0);
    }
  }
  __builtin_amdgcn_s_setprio(0);
}

// stage-0 variant: f-gate dead (c=0) -> only i,g,o
__device__ __forceinline__ void gate_gemm3(const unsigned short* sA, const unsigned short* pkB,
                                           int nt0, int lane, f32x4 (&acc)[2][3])
{
  const bf16x8* B = (const bf16x8*)pkB;
  const int g16  = (lane >> 4) << 3;
  const int swz  = (lane & 7) << 3;
  const int rbase = lane & 15;
  __builtin_amdgcn_s_setprio(1);
  #pragma unroll
  for (int kc = 0; kc < 8; ++kc){
    bf16x8 b0 = B[(nt0     ) * 512 + kc * 64 + lane];
    bf16x8 b2 = B[(nt0 + 32) * 512 + kc * 64 + lane];
    bf16x8 b3 = B[(nt0 + 48) * 512 + kc * 64 + lane];
    int kcol = (kc * 32 + g16) ^ swz;
    #pragma unroll
    for (int mt = 0; mt < 2; ++mt){
      bf16x8 a = *(const bf16x8*)(sA + (mt * 16 + rbase) * 256 + kcol);
      acc[mt][0] = __builtin_amdgcn_mfma_f32_16x16x32_bf16(a, b0, acc[mt][0], 0, 0, 0);
      acc[mt][1] = __builtin_amdgcn_mfma_f32_16x16x32_bf16(a, b2, acc[mt][1], 0, 0, 0);
      acc[mt][2] = __builtin_amdgcn_mfma_f32_16x16x32_bf16(a, b3, acc[mt][2], 0, 0, 0);
    }
  }
  __builtin_amdgcn_s_setprio(0);
}

__device__ __forceinline__ void gemm1(const unsigned short* sA, const unsigned short* pkB,
                                      int nt, int lane, f32x4 (&acc)[2])
{
  const bf16x8* B = (const bf16x8*)pkB;
  const int g16  = (lane >> 4) << 3;
  const int swz  = (lane & 7) << 3;
  const int rbase = lane & 15;
  __builtin_amdgcn_s_setprio(1);
  #pragma unroll
  for (int kc = 0; kc < 8; ++kc){
    bf16x8 b = B[nt * 512 + kc * 64 + lane];
    int kcol = (kc * 32 + g16) ^ swz;
    #pragma unroll
    for (int mt = 0; mt < 2; ++mt){
      bf16x8 a = *(const bf16x8*)(sA + (mt * 16 + rbase) * 256 + kcol);
      acc[mt] = __builtin_amdgcn_mfma_f32_16x16x32_bf16(a, b, acc[mt], 0, 0, 0);
    }
  }
  __builtin_amdgcn_s_setprio(0);
}

// single 16-row block at row base mh*16 for the tiny out GEMMs
__device__ __forceinline__ void gemm1q(const unsigned short* sA, const unsigned short* pkB,
                                       int nt, int mh, int lane, f32x4 &acc)
{
  const bf16x8* B = (const bf16x8*)pkB;
  const int g16  = (lane >> 4) << 3;
  const int swz  = (lane & 7) << 3;
  const int rbase = mh * 16 + (lane & 15);
  __builtin_amdgcn_s_setprio(1);
  #pragma unroll
  for (int kc = 0; kc < 8; ++kc){
    bf16x8 b = B[nt * 512 + kc * 64 + lane];
    int kcol = (kc * 32 + g16) ^ swz;
    bf16x8 a = *(const bf16x8*)(sA + rbase * 256 + kcol);
    acc = __builtin_amdgcn_mfma_f32_16x16x32_bf16(a, b, acc, 0, 0, 0);
  }
  __builtin_amdgcn_s_setprio(0);
}

// ---------------------------------------------------------------------------
// (256,2): VGPR cap 128 -> 2 waves/SIMD; 64 KiB LDS -> 2 WG/CU, indep clocks.
__global__ __launch_bounds__(256, 2)
void lstm_fused(const float* __restrict__ x, const unsigned short* __restrict__ pk,
                const float* __restrict__ bih, const float* __restrict__ bhh,
                const float* __restrict__ hsb, const float* __restrict__ csb,
                const float* __restrict__ midb,
                const float* __restrict__ ob0, const float* __restrict__ ob1,
                const float* __restrict__ ob2, float* __restrict__ out)
{
  __shared__ __align__(16) unsigned short smem[32768];   // 64 KiB
  unsigned short* s_x  = smem;            // x (bf16)  [32][256]
  unsigned short* s_h0 = smem + 8192;     // h0, then hh
  unsigned short* s_h1 = smem + 16384;    // h1, then h2
  unsigned short* s_bu = smem + 24576;    // mid / c1 / f32 out staging

  const int tid  = threadIdx.x;
  const int lane = tid & 63;
  const int w    = tid >> 6;              // col quarter 0..3
  const int row0 = blockIdx.x * 32;
  const int rsub = (lane >> 4) << 2;
  const int jl   = lane & 15;

  // ---- stage x into LDS (f32 -> bf16, swizzled)
  {
    const float* xg = x + (size_t)row0 * 256;
    #pragma unroll
    for (int it = 0; it < 4; ++it){
      int idx = it * 2048 + tid * 8;
      int row = idx >> 8, col = idx & 255;
      float4 v0 = *(const float4*)(xg + idx);
      float4 v1 = *(const float4*)(xg + idx + 4);
      bf16x8 bv;
      bv[0]=(short)f2bf(v0.x); bv[1]=(short)f2bf(v0.y); bv[2]=(short)f2bf(v0.z); bv[3]=(short)f2bf(v0.w);
      bv[4]=(short)f2bf(v1.x); bv[5]=(short)f2bf(v1.y); bv[6]=(short)f2bf(v1.z); bv[7]=(short)f2bf(v1.w);
      *(bf16x8*)(s_x + row * 256 + (col ^ ((row & 7) << 3))) = bv;
    }
  }
  __syncthreads();

  float c0[4][2][4];   // c-state in regs: [t][mt][r]

  // ======== STAGE 0: gates from x only (h=c=0); f-gate skipped
  #pragma unroll
  for (int t = 0; t < 4; ++t){
    int jb = w * 64 + t * 16, nt0 = w * 4 + t, j = jb + jl;
    f32x4 acc[2][3] = {};
    gate_gemm3(s_x, pk + OFF_WIH, nt0, lane, acc);
    float bi = bih[j]       + bhh[j];
    float bg = bih[512 + j] + bhh[512 + j];
    float bo = bih[768 + j] + bhh[768 + j];
    #pragma unroll
    for (int mt = 0; mt < 2; ++mt){
      #pragma unroll
      for (int r = 0; r < 4; ++r){
        float c = sigm(acc[mt][0][r] + bi) * tanh_(acc[mt][1][r] + bg);
        float h = sigm(acc[mt][2][r] + bo) * tanh_(c);
        c0[t][mt][r] = c;
        int m = mt * 16 + rsub + r;
        s_h0[m * 256 + (j ^ ((m & 7) << 3))] = f2bf(h);
      }
    }
  }
  __syncthreads();

  // ======== MID0
  #pragma unroll
  for (int t = 0; t < 4; ++t){
    int jb = w * 64 + t * 16, j = jb + jl;
    f32x4 am[2] = {};
    gemm1(s_h0, pk + OFF_MID, w * 4 + t, lane, am);
    float mb = midb[j];
    #pragma unroll
    for (int mt = 0; mt < 2; ++mt){
      #pragma unroll
      for (int r = 0; r < 4; ++r){
        float mv = am[mt][r] + mb; mv = mv > 0.f ? mv : 0.f;
        int m = mt * 16 + rsub + r;
        s_bu[m * 256 + (j ^ ((m & 7) << 3))] = f2bf(mv);
      }
    }
  }
  __syncthreads();

  // ======== OUT0 (54 cols): wave w -> nt=w, rows 0..31
  {
    f32x4 ao[2] = {};
    gemm1(s_bu, pk + OFF_OUT0, w, lane, ao);
    __syncthreads();                        // s_bu reads done
    float* s_of = (float*)s_bu;
    int colc = w * 16 + jl;
    if (colc < 54){
      float ob = ob0[colc];
      #pragma unroll
      for (int mt = 0; mt < 2; ++mt)
        #pragma unroll
        for (int r = 0; r < 4; ++r){
          int m = mt * 16 + rsub + r;
          s_of[m * 54 + colc] = ao[mt][r] + ob;
        }
    }
    __syncthreads();
    float4* op = (float4*)(out + (size_t)row0 * 54);
    const float4* s4 = (const float4*)s_of;
    for (int e = tid; e < 432; e += 256) op[e] = s4[e];
  }
  __syncthreads();

  // ======== STAGE 1: gates from x and h0; uses c0
  #pragma unroll
  for (int t = 0; t < 4; ++t){
    int jb = w * 64 + t * 16, nt0 = w * 4 + t, j = jb + jl;
    f32x4 acc[2][4] = {};
    gate_gemm(s_x,  pk + OFF_WIH + 262144, nt0, lane, acc);
    gate_gemm(s_h0, pk + OFF_WHH,          nt0, lane, acc);
    float bi = bih[1024 + j]       + bhh[1024 + j];
    float bf_= bih[1024 + 256 + j] + bhh[1024 + 256 + j];
    float bg = bih[1024 + 512 + j] + bhh[1024 + 512 + j];
    float bo = bih[1024 + 768 + j] + bhh[1024 + 768 + j];
    #pragma unroll
    for (int mt = 0; mt < 2; ++mt){
      #pragma unroll
      for (int r = 0; r < 4; ++r){
        float c1 = sigm(acc[mt][1][r] + bf_) * c0[t][mt][r]
                 + sigm(acc[mt][0][r] + bi ) * tanh_(acc[mt][2][r] + bg);
        float h1 = sigm(acc[mt][3][r] + bo) * tanh_(c1);
        int m = mt * 16 + rsub + r;
        int ofs = m * 256 + (j ^ ((m & 7) << 3));
        s_h1[ofs] = f2bf(h1);
        s_bu[ofs] = f2bf(c1);
      }
    }
  }
  __syncthreads();

  // ======== HS/CS mix: hh = h0 + h1*hsW^T + hsb (in place); cc into c0 regs
  #pragma unroll
  for (int t = 0; t < 4; ++t){
    int jb = w * 64 + t * 16, nt = w * 4 + t, j = jb + jl;
    f32x4 ah[2] = {}, ac[2] = {};
    gemm1(s_h1, pk + OFF_HS, nt, lane, ah);
    gemm1(s_bu, pk + OFF_CS, nt, lane, ac);
    float hb = hsb[j], cb = csb[j];
    #pragma unroll
    for (int mt = 0; mt < 2; ++mt){
      #pragma unroll
      for (int r = 0; r < 4; ++r){
        int m = mt * 16 + rsub + r;
        int ofs = m * 256 + (j ^ ((m & 7) << 3));
        float hh = bf2f(s_h0[ofs]) + ah[mt][r] + hb;   // own slot: no race
        s_h0[ofs] = f2bf(hh);
        c0[t][mt][r] += ac[mt][r] + cb;
      }
    }
  }
  __syncthreads();

  // ======== MID1
  #pragma unroll
  for (int t = 0; t < 4; ++t){
    int jb = w * 64 + t * 16, j = jb + jl;
    f32x4 am[2] = {};
    gemm1(s_h1, pk + OFF_MID + 65536, w * 4 + t, lane, am);
    float mb = midb[256 + j];
    #pragma unroll
    for (int mt = 0; mt < 2; ++mt){
      #pragma unroll
      for (int r = 0; r < 4; ++r){
        float mv = am[mt][r] + mb; mv = mv > 0.f ? mv : 0.f;
        int m = mt * 16 + rsub + r;
        s_bu[m * 256 + (j ^ ((m & 7) << 3))] = f2bf(mv);
      }
    }
  }
  __syncthreads();

  // ======== OUT1 (23 cols): wave w -> nt=w&1, 16-row half mh=w>>1
  {
    f32x4 ao = {0.f, 0.f, 0.f, 0.f};
    gemm1q(s_bu, pk + OFF_OUT1, w & 1, w >> 1, lane, ao);
    __syncthreads();
    float* s_of = (float*)s_bu;
    int colc = (w & 1) * 16 + jl;
    if (colc < 23){
      float ob = ob1[colc];
      #pragma unroll
      for (int r = 0; r < 4; ++r){
        int m = (w >> 1) * 16 + rsub + r;
        s_of[m * 23 + colc] = ao[r] + ob;
      }
    }
    __syncthreads();
    float4* op = (float4*)(out + 3538944 + (size_t)row0 * 23);
    const float4* s4 = (const float4*)s_of;
    for (int e = tid; e < 184; e += 256) op[e] = s4[e];
  }
  __syncthreads();

  // ======== STAGE 2: gates from x and hh; uses cc (in c0)
  #pragma unroll
  for (int t = 0; t < 4; ++t){
    int jb = w * 64 + t * 16, nt0 = w * 4 + t, j = jb + jl;
    f32x4 acc[2][4] = {};
    gate_gemm(s_x,  pk + OFF_WIH + 524288, nt0, lane, acc);
    gate_gemm(s_h0, pk + OFF_WHH + 262144, nt0, lane, acc);
    float bi = bih[2048 + j]       + bhh[2048 + j];
    float bf_= bih[2048 + 256 + j] + bhh[2048 + 256 + j];
    float bg = bih[2048 + 512 + j] + bhh[2048 + 512 + j];
    float bo = bih[2048 + 768 + j] + bhh[2048 + 768 + j];
    #pragma unroll
    for (int mt = 0; mt < 2; ++mt){
      #pragma unroll
      for (int r = 0; r < 4; ++r){
        float c2 = sigm(acc[mt][1][r] + bf_) * c0[t][mt][r]
                 + sigm(acc[mt][0][r] + bi ) * tanh_(acc[mt][2][r] + bg);
        float h2 = sigm(acc[mt][3][r] + bo) * tanh_(c2);
        int m = mt * 16 + rsub + r;
        s_h1[m * 256 + (j ^ ((m & 7) << 3))] = f2bf(h2);
      }
    }
  }
  __syncthreads();

  // ======== MID2
  #pragma unroll
  for (int t = 0; t < 4; ++t){
    int jb = w * 64 + t * 16, j = jb + jl;
    f32x4 am[2] = {};
    gemm1(s_h1, pk + OFF_MID + 131072, w * 4 + t, lane, am);
    float mb = midb[512 + j];
    #pragma unroll
    for (int mt = 0; mt < 2; ++mt){
      #pragma unroll
      for (int r = 0; r < 4; ++r){
        float mv = am[mt][r] + mb; mv = mv > 0.f ? mv : 0.f;
        int m = mt * 16 + rsub + r;
        s_bu[m * 256 + (j ^ ((m & 7) << 3))] = f2bf(mv);
      }
    }
  }
  __syncthreads();

  // ======== OUT2 (20 cols)
  {
    f32x4 ao = {0.f, 0.f, 0.f, 0.f};
    gemm1q(s_bu, pk + OFF_OUT2, w & 1, w >> 1, lane, ao);
    __syncthreads();
    float* s_of = (float*)s_bu;
    int colc = (w & 1) * 16 + jl;
    if (colc < 20){
      float ob = ob2[colc];
      #pragma unroll
      for (int r = 0; r < 4; ++r){
        int m = (w >> 1) * 16 + rsub + r;
        s_of[m * 20 + colc] = ao[r] + ob;
      }
    }
    __syncthreads();
    float4* op = (float4*)(out + 5046272 + (size_t)row0 * 20);
    const float4* s4 = (const float4*)s_of;
    for (int e = tid; e < 160; e += 256) op[e] = s4[e];
  }
}

extern "C" void kernel_launch(void* const* d_in, const int* in_sizes, int n_in,
                              void* d_out, int out_size, void* d_ws, size_t ws_size,
                              hipStream_t stream)
{
  const float* x     = (const float*)d_in[0];
  const float* Wih   = (const float*)d_in[1];
  const float* Whh   = (const float*)d_in[2];
  const float* bih   = (const float*)d_in[3];
  const float* bhh   = (const float*)d_in[4];
  const float* hsW   = (const float*)d_in[5];
  const float* hsb   = (const float*)d_in[6];
  const float* csW   = (const float*)d_in[7];
  const float* csb   = (const float*)d_in[8];
  const float* midW  = (const float*)d_in[9];
  const float* midb  = (const float*)d_in[10];
  const float* outW0 = (const float*)d_in[11];
  const float* outb0 = (const float*)d_in[12];
  const float* outW1 = (const float*)d_in[13];
  const float* outb1 = (const float*)d_in[14];
  const float* outW2 = (const float*)d_in[15];
  const float* outb2 = (const float*)d_in[16];

  unsigned short* pk = (unsigned short*)d_ws;

  int ngroups = PK_TOTAL / 8;
  pack_all<<<(ngroups + 255) / 256, 256, 0, stream>>>(
      Wih, Whh, hsW + 5 * 65536, csW + 5 * 65536, midW, outW0, outW1, outW2, pk);

  lstm_fused<<<2048, 256, 0, stream>>>(
      x, pk, bih, bhh, hsb + 5 * 256, csb + 5 * 256, midb,
      outb0, outb1, outb2, (float*)d_out);
}